// Round 12
// baseline (690.844 us; speedup 1.0000x reference)
//
#include <hip/hip_runtime.h>
#include <hip/hip_bf16.h>
#include <math.h>

#define HEADS 8
#define NEG_SLOPE 0.2f
#define BSHIFT 6
#define SLACK 2048

typedef __attribute__((ext_vector_type(8))) short short8v;
typedef __attribute__((ext_vector_type(4))) float f32x4;

__device__ __forceinline__ float bf2f(unsigned short u) {
    return __uint_as_float(((unsigned int)u) << 16);
}
__device__ __forceinline__ unsigned short f2bf(float f) {
    __hip_bfloat16 h = __float2bfloat16(f);
    union { __hip_bfloat16 h; unsigned short u; } c; c.h = h; return c.u;
}

// ---------------------------------------------------------------- CSR build, pass A:
// deg count + bucket-binned edge records (full-line writes, no 4B scatter).
__global__ void k_binA(const int* __restrict__ ei, int* __restrict__ deg,
                       int* __restrict__ bcnt, int2* __restrict__ rec, int E) {
    int i = blockIdx.x * 256 + threadIdx.x;
    if (i >= E) return;
    int s = ei[i], d = ei[E + i];
    atomicAdd(&deg[d], 1);
    int b = d >> BSHIFT;
    int pos = atomicAdd(&bcnt[b], 1);
    if (pos < SLACK) rec[(size_t)b * SLACK + pos] = make_int2(s, d);
}

// deg[] holds edge counts (zeroed by memset); +1 here accounts the self-loop.
__global__ void k_scan_block(const int* __restrict__ deg, int* __restrict__ offs,
                             int* __restrict__ bsum, int N) {
    __shared__ int lds[256];
    int tid = threadIdx.x;
    int base = blockIdx.x * 1024 + tid * 4;
    int v0 = (base + 0 < N) ? deg[base + 0] + 1 : 0;
    int v1 = (base + 1 < N) ? deg[base + 1] + 1 : 0;
    int v2 = (base + 2 < N) ? deg[base + 2] + 1 : 0;
    int v3 = (base + 3 < N) ? deg[base + 3] + 1 : 0;
    int t01 = v0 + v1;
    int tot = t01 + v2 + v3;
    lds[tid] = tot;
    __syncthreads();
    for (int off = 1; off < 256; off <<= 1) {
        int x = 0;
        if (tid >= off) x = lds[tid - off];
        __syncthreads();
        lds[tid] += x;
        __syncthreads();
    }
    int ex = lds[tid] - tot;
    if (tid == 255) bsum[blockIdx.x] = lds[255];
    if (base + 0 < N) offs[base + 0] = ex;
    if (base + 1 < N) offs[base + 1] = ex + v0;
    if (base + 2 < N) offs[base + 2] = ex + t01;
    if (base + 3 < N) offs[base + 3] = ex + t01 + v2;
}

// single 256-thread block scan over nb (<=256) block sums
__global__ void k_scan_top(int* __restrict__ bsum, int nb) {
    __shared__ int lds[256];
    int tid = threadIdx.x;
    int v = (tid < nb) ? bsum[tid] : 0;
    lds[tid] = v;
    __syncthreads();
    for (int off = 1; off < 256; off <<= 1) {
        int x = 0;
        if (tid >= off) x = lds[tid - off];
        __syncthreads();
        lds[tid] += x;
        __syncthreads();
    }
    if (tid < nb) bsum[tid] = lds[tid] - v;  // exclusive
    if (tid == 0) bsum[nb] = lds[255];       // total
}

__global__ void k_scan_add(int* __restrict__ offs, const int* __restrict__ bsum, int N) {
    int i = blockIdx.x * 256 + threadIdx.x;
    if (i < N) offs[i] += bsum[i >> 10];
    if (i == 0) offs[N] = bsum[(N + 1023) >> 10];
}

// ---------------------------------------------------------------- CSR build, pass B:
// one block per bucket; LDS-ranked scatter into a small contiguous csr window.
__global__ __launch_bounds__(256) void k_binB(
    const int2* __restrict__ rec, const int* __restrict__ bcnt,
    const int* __restrict__ offs, int* __restrict__ csr, int N) {
    __shared__ int loff[64];
    __shared__ int lcnt[64];
    int b = blockIdx.x;
    int tid = threadIdx.x;
    int n0 = b << BSHIFT;
    if (tid < 64) {
        lcnt[tid] = 0;
        int n = n0 + tid;
        if (n < N) {
            int o = offs[n];
            loff[tid] = o;
            csr[o] = n;          // self-loop first
        }
    }
    __syncthreads();
    int cnt = min(bcnt[b], SLACK);
    const int2* base = rec + (size_t)b * SLACK;
    for (int i = tid; i < cnt; i += 256) {
        int2 r = base[i];
        int l = r.y & 63;
        int rank = atomicAdd(&lcnt[l], 1);
        csr[loff[l] + 1 + rank] = r.x;
    }
}

// ---------------------------------------------------------------- dual GEMM (+ optional AL fold)
template <int CPT, int M1, int M2, bool AL_FOLD, bool A_BF16>
__global__ __launch_bounds__(256) void k_gemm_dual(
    const float* __restrict__ X, const float* __restrict__ Wa, const float* __restrict__ Wb,
    const float* __restrict__ bias1, const float* __restrict__ bias2,
    void* __restrict__ outa_, float* __restrict__ outb,
    const float* __restrict__ as_w, const float* __restrict__ ad_w, float* __restrict__ AL,
    int N, int K) {
    constexpr int M = M1 + M2;
    static_assert(CPT * 16 >= M, "CPT too small");
    __shared__ float sW[CPT * 16][68];
    __shared__ float sX[64][68];
    int tx = threadIdx.x, ty = threadIdx.y;
    int tid = ty * 16 + tx;
    int r0 = blockIdx.x * 64;

    float acc[4][CPT];
#pragma unroll
    for (int jc = 0; jc < CPT; ++jc) {
        int col = tx + 16 * jc;
        float b = 0.f;
        if (col >= M1 && col < M) b = bias1[col - M1] + bias2[col - M1];
#pragma unroll
        for (int jr = 0; jr < 4; ++jr) acc[jr][jc] = b;
    }

    for (int k0 = 0; k0 < K; k0 += 64) {
        __syncthreads();
        for (int idx = tid; idx < CPT * 16 * 16; idx += 256) {
            int c = idx >> 4, kq = (idx & 15) * 4;
            float4 v = make_float4(0.f, 0.f, 0.f, 0.f);
            if (c < M1) v = *(const float4*)&Wa[(size_t)c * K + k0 + kq];
            else if (c < M) v = *(const float4*)&Wb[(size_t)(c - M1) * K + k0 + kq];
            *(float4*)&sW[c][kq] = v;
        }
        for (int idx = tid; idx < 64 * 16; idx += 256) {
            int r = idx >> 4, kq = (idx & 15) * 4;
            int gr = r0 + r;
            float4 v = make_float4(0.f, 0.f, 0.f, 0.f);
            if (gr < N) v = *(const float4*)&X[(size_t)gr * K + k0 + kq];
            *(float4*)&sX[r][kq] = v;
        }
        __syncthreads();

        for (int k = 0; k < 64; k += 4) {
            float4 xr[4];
#pragma unroll
            for (int jr = 0; jr < 4; ++jr) xr[jr] = *(const float4*)&sX[ty * 4 + jr][k];
#pragma unroll
            for (int jc = 0; jc < CPT; ++jc) {
                float4 wc = *(const float4*)&sW[tx + 16 * jc][k];
#pragma unroll
                for (int jr = 0; jr < 4; ++jr)
                    acc[jr][jc] += wc.x * xr[jr].x + wc.y * xr[jr].y +
                                   wc.z * xr[jr].z + wc.w * xr[jr].w;
            }
        }
    }

#pragma unroll
    for (int jr = 0; jr < 4; ++jr) {
        int gr = r0 + ty * 4 + jr;
        if (gr >= N) continue;
#pragma unroll
        for (int jc = 0; jc < CPT; ++jc) {
            int col = tx + 16 * jc;
            if (col < M1) {
                if (A_BF16) ((unsigned short*)outa_)[(size_t)gr * M1 + col] = f2bf(acc[jr][jc]);
                else        ((float*)outa_)[(size_t)gr * M1 + col] = acc[jr][jc];
            } else if (col < M) {
                outb[(size_t)gr * M2 + (col - M1)] = acc[jr][jc];
            }
        }
    }

    if constexpr (AL_FOLD) {
        __syncthreads();
        float* sH = &sW[0][0];  // reuse as sH[64][68]
#pragma unroll
        for (int jr = 0; jr < 4; ++jr)
#pragma unroll
            for (int jc = 0; jc < 4; ++jc)
                sH[(ty * 4 + jr) * 68 + (tx + 16 * jc)] = acc[jr][jc];
        __syncthreads();
        int j = tid & 15, hd = j & 7;
        const float* a = (j < 8 ? as_w : ad_w) + hd * 8;
        float av[8];
#pragma unroll
        for (int c = 0; c < 8; ++c) av[c] = a[c];
#pragma unroll
        for (int q = 0; q < 4; ++q) {
            int row = (tid >> 4) + 16 * q;
            int gr = r0 + row;
            if (gr < N) {
                float sum = 0.f;
#pragma unroll
                for (int c = 0; c < 8; ++c) sum += av[c] * sH[row * 68 + hd * 8 + c];
                AL[(size_t)gr * 16 + j] = sum;
            }
        }
    }
}

// ---------------------------------------------------------------- layer-2 constant prep
__global__ void k_prep2(const float* __restrict__ W2, const float* __restrict__ as2,
                        const float* __restrict__ ad2, float* __restrict__ wt,
                        __hip_bfloat16* __restrict__ w2sw) {
    if (blockIdx.x < 96) {
        int t = blockIdx.x * 256 + threadIdx.x;
        int j = t & 7;
        int rc = t >> 3;
        int col = rc % 48, c = rc / 48;
        int k = c * 8 + j;
        int hd = k >> 6, kk = k & 63;
        float v = (col < 40) ? W2[(size_t)(hd * 40 + col) * 64 + kk] : 0.f;
        w2sw[t] = __float2bfloat16(v);
    } else {
        for (int t = threadIdx.x; t < 1024; t += 256) {
            int j = t >> 6, k = t & 63;
            int hd = j & 7;
            const float* a = (j < 8 ? as2 : ad2) + hd * 40;
            float sum = 0.f;
            for (int c = 0; c < 40; ++c) sum += a[c] * W2[(size_t)(hd * 40 + c) * 64 + k];
            wt[j * 64 + k] = sum;
        }
    }
}

// ---------------------------------------------------------------- layers 0/1: no-max softmax-aggregate, bf16 rows, paired-dim layout
__global__ __launch_bounds__(256, 8) void k_fused(
    const unsigned short* __restrict__ Hb, const float* __restrict__ AL,
    const int* __restrict__ offs, const int* __restrict__ csr,
    float* __restrict__ S, unsigned short* __restrict__ Sb, int N) {
    int wid = threadIdx.x >> 6, lane = threadIdx.x & 63;
    int n = blockIdx.x * 4 + wid;
    if (n >= N) return;
    int off = offs[n], deg = offs[n + 1] - off;
    int el = lane >> 3, hd = lane & 7;
    int dp = lane & 31, es = lane >> 5;
    int hp = dp >> 2;  // head of dims (2dp,2dp+1)
    float ald = AL[(size_t)n * 16 + 8 + hd];

    int src_c = 0; float e_c = 0.f;
    if (el < deg) {
        src_c = csr[off + el];
        float t = AL[(size_t)src_c * 16 + hd] + ald;
        e_c = __expf(t > 0.f ? t : NEG_SLOPE * t);
    }

    float s_run = 0.f, ax = 0.f, ay = 0.f;
    for (int b0 = 0; b0 < deg; b0 += 8) {
        unsigned int hv[4];
#pragma unroll
        for (int j = 0; j < 4; ++j) {
            int sj = __shfl(src_c, (2 * j + es) * 8);
            hv[j] = *(const unsigned int*)&Hb[(size_t)sj * 64 + 2 * dp];
        }
        // prefetch next block's (src, e)
        int en = b0 + 8 + el;
        int src_n = 0; float e_n = 0.f;
        if (en < deg) {
            src_n = csr[off + en];
            float t = AL[(size_t)src_n * 16 + hd] + ald;
            e_n = __expf(t > 0.f ? t : NEG_SLOPE * t);
        }

        s_run += e_c;  // lane-local; reduced after the loop
#pragma unroll
        for (int j = 0; j < 4; ++j) {
            float a = __shfl(e_c, (2 * j + es) * 8 + hp);
            unsigned int u = hv[j];
            ax += a * bf2f((unsigned short)(u & 0xffff));
            ay += a * bf2f((unsigned short)(u >> 16));
        }
        src_c = src_n; e_c = e_n;
    }
#pragma unroll
    for (int d = 8; d <= 32; d <<= 1) s_run += __shfl_xor(s_run, d);
    float sf = __shfl(s_run, hp);
    float inv = 1.0f / (sf + 1e-16f);
    ax *= inv; ay *= inv;
    ax += __shfl_xor(ax, 32);
    ay += __shfl_xor(ay, 32);
    if (es == 0) {
        float2 sk = *(const float2*)&S[(size_t)n * 64 + 2 * dp];
        float vx = sk.x + ax, vy = sk.y + ay;
        vx = vx > 0.f ? vx : expm1f(vx);
        vy = vy > 0.f ? vy : expm1f(vy);
        *(float2*)&S[(size_t)n * 64 + 2 * dp] = make_float2(vx, vy);
        if (Sb) {
            ushort2 w;
            w.x = f2bf(vx); w.y = f2bf(vy);
            *(ushort2*)&Sb[(size_t)n * 64 + 2 * dp] = w;
        }
    }
}

// ---------------------------------------------------------------- layer 2: no-max aggregate, bf16 rows, head-split -> bf16 LDS -> MFMA
__global__ __launch_bounds__(256, 8) void k_l2f(
    const unsigned short* __restrict__ Xb, const float* __restrict__ AL,
    const float* __restrict__ SK, const __hip_bfloat16* __restrict__ w2sw,
    const int* __restrict__ offs, const int* __restrict__ csr,
    float* __restrict__ out, int N) {
    __shared__ __hip_bfloat16 sA[64 * 16 * 8];  // [chunk][rot-row][8], 16 KB
    __shared__ float sC[16][48];                // 3 KB
    __shared__ float sW8[4][64];                // per-wave alpha row, 1 KB
    int wid = threadIdx.x >> 6, lane = threadIdx.x & 63;
    int el = lane >> 3, hd = lane & 7;
    int dp = lane & 31, eh = lane >> 5;

#pragma unroll 1
    for (int p = 0; p < 4; ++p) {
        int mrow = wid * 4 + p;
        int n = blockIdx.x * 16 + mrow;
        float2 acc[4];
#pragma unroll
        for (int h2 = 0; h2 < 4; ++h2) acc[h2] = make_float2(0.f, 0.f);
        if (n < N) {
            int off = offs[n], deg = offs[n + 1] - off;
            float ald = AL[(size_t)n * 16 + 8 + hd];

            int src_c = 0; float e_c = 0.f;
            if (el < deg) {
                src_c = csr[off + el];
                float t = AL[(size_t)src_c * 16 + hd] + ald;
                e_c = __expf(t > 0.f ? t : NEG_SLOPE * t);
            }

            float s_run = 0.f;
#pragma unroll 1
            for (int b0 = 0; b0 < deg; b0 += 8) {
                unsigned int xv0[4];
#pragma unroll
                for (int j = 0; j < 4; ++j) {
                    int sj = __shfl(src_c, j * 8);
                    xv0[j] = *(const unsigned int*)&Xb[(size_t)sj * 64 + 2 * dp];
                }
                // prefetch next block's (src, e)
                int en = b0 + 8 + el;
                int src_n = 0; float e_n = 0.f;
                if (en < deg) {
                    src_n = csr[off + en];
                    float t = AL[(size_t)src_n * 16 + hd] + ald;
                    e_n = __expf(t > 0.f ? t : NEG_SLOPE * t);
                }

                sW8[wid][lane] = e_c;  // stats layout [e&7]*8+hd, same-wave consume
                s_run += e_c;
#pragma unroll
                for (int j = 0; j < 4; ++j) {
                    float4 a4 = *(const float4*)&sW8[wid][j * 8 + 4 * eh];
                    float hx = bf2f((unsigned short)(xv0[j] & 0xffff));
                    float hy = bf2f((unsigned short)(xv0[j] >> 16));
                    acc[0].x += a4.x * hx; acc[0].y += a4.x * hy;
                    acc[1].x += a4.y * hx; acc[1].y += a4.y * hy;
                    acc[2].x += a4.z * hx; acc[2].y += a4.z * hy;
                    acc[3].x += a4.w * hx; acc[3].y += a4.w * hy;
                }
#pragma unroll
                for (int j = 0; j < 4; ++j) {
                    int sj = __shfl(src_c, (j + 4) * 8);
                    xv0[j] = *(const unsigned int*)&Xb[(size_t)sj * 64 + 2 * dp];
                }
#pragma unroll
                for (int j = 0; j < 4; ++j) {
                    float4 a4 = *(const float4*)&sW8[wid][(j + 4) * 8 + 4 * eh];
                    float hx = bf2f((unsigned short)(xv0[j] & 0xffff));
                    float hy = bf2f((unsigned short)(xv0[j] >> 16));
                    acc[0].x += a4.x * hx; acc[0].y += a4.x * hy;
                    acc[1].x += a4.y * hx; acc[1].y += a4.y * hy;
                    acc[2].x += a4.z * hx; acc[2].y += a4.z * hy;
                    acc[3].x += a4.w * hx; acc[3].y += a4.w * hy;
                }
                src_c = src_n; e_c = e_n;
            }
#pragma unroll
            for (int d = 8; d <= 32; d <<= 1) s_run += __shfl_xor(s_run, d);
#pragma unroll
            for (int h2 = 0; h2 < 4; ++h2) {
                float sv = __shfl(s_run, 4 * eh + h2);
                float iv = 1.0f / (sv + 1e-16f);
                acc[h2].x *= iv; acc[h2].y *= iv;
            }
        }
#pragma unroll
        for (int h2 = 0; h2 < 4; ++h2) {
            int K0 = (4 * eh + h2) * 64 + 2 * dp;
            int chunk = K0 >> 3, pos = K0 & 7;
            ushort2 w;
            w.x = f2bf(acc[h2].x); w.y = f2bf(acc[h2].y);
            *(ushort2*)&sA[chunk * 128 + ((mrow + chunk) & 15) * 8 + pos] = w;
        }
    }
    __syncthreads();

    // ---- MFMA projection: waves 0..2 each one 16-col N-tile, K=512
    if (wid < 3) {
        f32x4 cacc = {0.f, 0.f, 0.f, 0.f};
        int grp = lane >> 4;
        int r16 = lane & 15;
#pragma unroll 4
        for (int ks = 0; ks < 16; ++ks) {
            int c = ks * 4 + grp;
            short8v av = *(const short8v*)&sA[c * 128 + ((r16 + c) & 15) * 8];
            short8v bv = *(const short8v*)&w2sw[(size_t)(c * 48 + wid * 16 + r16) * 8];
            cacc = __builtin_amdgcn_mfma_f32_16x16x32_bf16(av, bv, cacc, 0, 0, 0);
        }
#pragma unroll
        for (int jj = 0; jj < 4; ++jj)
            sC[grp * 4 + jj][wid * 16 + r16] = cacc[jj];
    }
    __syncthreads();

    // ---- epilogue: + skip, log_softmax over 40 outputs
    for (int p = 0; p < 4; ++p) {
        int mrow = wid * 4 + p;
        int n = blockIdx.x * 16 + mrow;
        if (n >= N) continue;
        float val = (lane < 40) ? SK[(size_t)n * 40 + lane] + sC[mrow][lane] * 0.125f : -INFINITY;
        float mx = val;
#pragma unroll
        for (int d = 32; d; d >>= 1) mx = fmaxf(mx, __shfl_xor(mx, d));
        float ex = (lane < 40) ? __expf(val - mx) : 0.f;
        float sm = ex;
#pragma unroll
        for (int d = 32; d; d >>= 1) sm += __shfl_xor(sm, d);
        if (lane < 40) out[(size_t)n * 40 + lane] = val - mx - logf(sm);
    }
}

// ---------------------------------------------------------------- launch
extern "C" void kernel_launch(void* const* d_in, const int* in_sizes, int n_in,
                              void* d_out, int out_size, void* d_ws, size_t ws_size,
                              hipStream_t stream) {
    const float* x   = (const float*)d_in[0];
    const int*   ei  = (const int*)d_in[1];
    const float* W0  = (const float*)d_in[2];
    const float* as0 = (const float*)d_in[3];
    const float* ad0 = (const float*)d_in[4];
    const float* b0  = (const float*)d_in[5];
    const float* sW0 = (const float*)d_in[6];
    const float* sb0 = (const float*)d_in[7];
    const float* W1  = (const float*)d_in[8];
    const float* as1 = (const float*)d_in[9];
    const float* ad1 = (const float*)d_in[10];
    const float* b1  = (const float*)d_in[11];
    const float* sW1 = (const float*)d_in[12];
    const float* sb1 = (const float*)d_in[13];
    const float* W2  = (const float*)d_in[14];
    const float* as2 = (const float*)d_in[15];
    const float* ad2 = (const float*)d_in[16];
    const float* b2  = (const float*)d_in[17];
    const float* sW2 = (const float*)d_in[18];
    const float* sb2 = (const float*)d_in[19];
    float* out = (float*)d_out;

    int N = in_sizes[0] / 128;
    int E = in_sizes[1] / 2;
    int NB = (N + 63) >> BSHIFT;

    char* wsp = (char*)d_ws;
    size_t woff = 0;
    auto A = [&](size_t nbytes) -> void* {
        void* p = wsp + woff;
        woff = (woff + nbytes + 255) & ~(size_t)255;
        return p;
    };
    int* offs   = (int*)A((size_t)(N + 1) * 4);
    int* deg    = (int*)A((size_t)N * 4);
    int* bsum   = (int*)A(4096);
    int* bcnt   = (int*)A((size_t)(NB + 1) * 4);
    int* csr    = (int*)A((size_t)(E + N) * 4);
    int2* rec   = (int2*)A((size_t)NB * SLACK * 8);
    float* wt   = (float*)A(1024 * 4);
    __hip_bfloat16* w2sw = (__hip_bfloat16*)A(64 * 48 * 8 * 2);
    float* AL   = (float*)A((size_t)N * 16 * 4);
    float* S    = (float*)A((size_t)N * 64 * 4);
    float* T    = (float*)A((size_t)N * 64 * 4);
    unsigned short* Hb = (unsigned short*)A((size_t)N * 64 * 2);
    unsigned short* Tb = (unsigned short*)A((size_t)N * 64 * 2);
    (void)ws_size; (void)n_in; (void)out_size;

    // ---- CSR build (bucketed, amplification-free)
    hipMemsetAsync(deg, 0, (size_t)N * 4, stream);
    hipMemsetAsync(bcnt, 0, (size_t)(NB + 1) * 4, stream);
    k_binA<<<(E + 255) / 256, 256, 0, stream>>>(ei, deg, bcnt, rec, E);
    int nb = (N + 1023) / 1024;
    k_scan_block<<<nb, 256, 0, stream>>>(deg, offs, bsum, N);
    k_scan_top<<<1, 256, 0, stream>>>(bsum, nb);
    k_scan_add<<<(N + 255) / 256, 256, 0, stream>>>(offs, bsum, N);
    k_binB<<<NB, 256, 0, stream>>>(rec, bcnt, offs, csr, N);

    // ---- layer-2 constants (independent)
    k_prep2<<<97, 256, 0, stream>>>(W2, as2, ad2, wt, w2sw);

    dim3 bG(16, 16);
    int gG = (N + 63) / 64;
    int gN4 = (N + 3) / 4;

    // ---- layer 0 (input x [N,128]): Hb + S(skip+biases) + AL in one GEMM
    k_gemm_dual<8, 64, 64, true, true><<<gG, bG, 0, stream>>>(
        x, W0, sW0, b0, sb0, Hb, S, as0, ad0, AL, N, 128);
    k_fused<<<gN4, 256, 0, stream>>>(Hb, AL, offs, csr, S, nullptr, N);  // S <- x1

    // ---- layer 1 (input S [N,64])
    k_gemm_dual<8, 64, 64, true, true><<<gG, bG, 0, stream>>>(
        S, W1, sW1, b1, sb1, Hb, T, as1, ad1, AL, N, 64);
    k_fused<<<gN4, 256, 0, stream>>>(Hb, AL, offs, csr, T, Tb, N);       // T <- x2 (+bf16 Tb)

    // ---- layer 2 (input T [N,64]): AL(wt part) + S(skip) in one GEMM
    k_gemm_dual<4, 16, 40, false, false><<<gG, bG, 0, stream>>>(
        T, wt, sW2, b2, sb2, AL, S, nullptr, nullptr, nullptr, N, 64);
    k_l2f<<<(N + 15) / 16, 256, 0, stream>>>(Tb, AL, S, w2sw, offs, csr, out, N);
}

// Round 13
// 552.881 us; speedup vs baseline: 1.2495x; 1.2495x over previous
//
#include <hip/hip_runtime.h>
#include <hip/hip_bf16.h>
#include <math.h>

#define HEADS 8
#define NEG_SLOPE 0.2f
#define BSHIFT 6
#define SLACK8 384

typedef __attribute__((ext_vector_type(8))) short short8v;
typedef __attribute__((ext_vector_type(4))) float f32x4;

__device__ __forceinline__ float bf2f(unsigned short u) {
    return __uint_as_float(((unsigned int)u) << 16);
}
__device__ __forceinline__ unsigned short f2bf(float f) {
    __hip_bfloat16 h = __float2bfloat16(f);
    union { __hip_bfloat16 h; unsigned short u; } c; c.h = h; return c.u;
}

// ---------------------------------------------------------------- CSR build, pass A:
// deg count + XCD-sliced bucket binning. Cell (b, x = blockIdx&7) is appended
// only by blocks on one XCD (round-robin dispatch) -> tail line stays in that
// XCD's L2, 8 records fill a 64B line before writeback.
__global__ void k_binA(const int* __restrict__ ei, int* __restrict__ deg,
                       int* __restrict__ bcnt, int2* __restrict__ rec, int E) {
    int i = blockIdx.x * 256 + threadIdx.x;
    if (i >= E) return;
    int x = blockIdx.x & 7;
    int s = ei[i], d = ei[E + i];
    atomicAdd(&deg[d], 1);
    int cell = ((d >> BSHIFT) << 3) + x;
    int pos = atomicAdd(&bcnt[cell], 1);
    if (pos < SLACK8) rec[(size_t)cell * SLACK8 + pos] = make_int2(s, d);
}

// deg[] holds edge counts (zeroed by memset); +1 here accounts the self-loop.
__global__ void k_scan_block(const int* __restrict__ deg, int* __restrict__ offs,
                             int* __restrict__ bsum, int N) {
    __shared__ int lds[256];
    int tid = threadIdx.x;
    int base = blockIdx.x * 1024 + tid * 4;
    int v0 = (base + 0 < N) ? deg[base + 0] + 1 : 0;
    int v1 = (base + 1 < N) ? deg[base + 1] + 1 : 0;
    int v2 = (base + 2 < N) ? deg[base + 2] + 1 : 0;
    int v3 = (base + 3 < N) ? deg[base + 3] + 1 : 0;
    int t01 = v0 + v1;
    int tot = t01 + v2 + v3;
    lds[tid] = tot;
    __syncthreads();
    for (int off = 1; off < 256; off <<= 1) {
        int x = 0;
        if (tid >= off) x = lds[tid - off];
        __syncthreads();
        lds[tid] += x;
        __syncthreads();
    }
    int ex = lds[tid] - tot;
    if (tid == 255) bsum[blockIdx.x] = lds[255];
    if (base + 0 < N) offs[base + 0] = ex;
    if (base + 1 < N) offs[base + 1] = ex + v0;
    if (base + 2 < N) offs[base + 2] = ex + t01;
    if (base + 3 < N) offs[base + 3] = ex + t01 + v2;
}

// single 256-thread block scan over nb (<=256) block sums
__global__ void k_scan_top(int* __restrict__ bsum, int nb) {
    __shared__ int lds[256];
    int tid = threadIdx.x;
    int v = (tid < nb) ? bsum[tid] : 0;
    lds[tid] = v;
    __syncthreads();
    for (int off = 1; off < 256; off <<= 1) {
        int x = 0;
        if (tid >= off) x = lds[tid - off];
        __syncthreads();
        lds[tid] += x;
        __syncthreads();
    }
    if (tid < nb) bsum[tid] = lds[tid] - v;  // exclusive
    if (tid == 0) bsum[nb] = lds[255];       // total
}

__global__ void k_scan_add(int* __restrict__ offs, const int* __restrict__ bsum, int N) {
    int i = blockIdx.x * 256 + threadIdx.x;
    if (i < N) offs[i] += bsum[i >> 10];
    if (i == 0) offs[N] = bsum[(N + 1023) >> 10];
}

// ---------------------------------------------------------------- CSR build, pass B:
// one block per bucket; dense cell reads, LDS-ranked writes into the bucket's
// contiguous csr window (stays in the block's XCD L2).
__global__ __launch_bounds__(256) void k_binB(
    const int2* __restrict__ rec, const int* __restrict__ bcnt,
    const int* __restrict__ offs, int* __restrict__ csr, int N) {
    __shared__ int loff[64];
    __shared__ int lcnt[64];
    int b = blockIdx.x;
    int tid = threadIdx.x;
    int n0 = b << BSHIFT;
    if (tid < 64) {
        lcnt[tid] = 0;
        int n = n0 + tid;
        if (n < N) {
            int o = offs[n];
            loff[tid] = o;
            csr[o] = n;          // self-loop first
        }
    }
    __syncthreads();
#pragma unroll 1
    for (int x = 0; x < 8; ++x) {
        int cell = (b << 3) + x;
        int cnt = min(bcnt[cell], SLACK8);
        const int2* base = rec + (size_t)cell * SLACK8;
        for (int i = tid; i < cnt; i += 256) {
            int2 r = base[i];
            int l = r.y & 63;
            int rank = atomicAdd(&lcnt[l], 1);
            csr[loff[l] + 1 + rank] = r.x;
        }
    }
}

// ---------------------------------------------------------------- dual GEMM (+ optional AL fold)
template <int CPT, int M1, int M2, bool AL_FOLD, bool A_BF16>
__global__ __launch_bounds__(256) void k_gemm_dual(
    const float* __restrict__ X, const float* __restrict__ Wa, const float* __restrict__ Wb,
    const float* __restrict__ bias1, const float* __restrict__ bias2,
    void* __restrict__ outa_, float* __restrict__ outb,
    const float* __restrict__ as_w, const float* __restrict__ ad_w, float* __restrict__ AL,
    int N, int K) {
    constexpr int M = M1 + M2;
    static_assert(CPT * 16 >= M, "CPT too small");
    __shared__ float sW[CPT * 16][68];
    __shared__ float sX[64][68];
    int tx = threadIdx.x, ty = threadIdx.y;
    int tid = ty * 16 + tx;
    int r0 = blockIdx.x * 64;

    float acc[4][CPT];
#pragma unroll
    for (int jc = 0; jc < CPT; ++jc) {
        int col = tx + 16 * jc;
        float b = 0.f;
        if (col >= M1 && col < M) b = bias1[col - M1] + bias2[col - M1];
#pragma unroll
        for (int jr = 0; jr < 4; ++jr) acc[jr][jc] = b;
    }

    for (int k0 = 0; k0 < K; k0 += 64) {
        __syncthreads();
        for (int idx = tid; idx < CPT * 16 * 16; idx += 256) {
            int c = idx >> 4, kq = (idx & 15) * 4;
            float4 v = make_float4(0.f, 0.f, 0.f, 0.f);
            if (c < M1) v = *(const float4*)&Wa[(size_t)c * K + k0 + kq];
            else if (c < M) v = *(const float4*)&Wb[(size_t)(c - M1) * K + k0 + kq];
            *(float4*)&sW[c][kq] = v;
        }
        for (int idx = tid; idx < 64 * 16; idx += 256) {
            int r = idx >> 4, kq = (idx & 15) * 4;
            int gr = r0 + r;
            float4 v = make_float4(0.f, 0.f, 0.f, 0.f);
            if (gr < N) v = *(const float4*)&X[(size_t)gr * K + k0 + kq];
            *(float4*)&sX[r][kq] = v;
        }
        __syncthreads();

        for (int k = 0; k < 64; k += 4) {
            float4 xr[4];
#pragma unroll
            for (int jr = 0; jr < 4; ++jr) xr[jr] = *(const float4*)&sX[ty * 4 + jr][k];
#pragma unroll
            for (int jc = 0; jc < CPT; ++jc) {
                float4 wc = *(const float4*)&sW[tx + 16 * jc][k];
#pragma unroll
                for (int jr = 0; jr < 4; ++jr)
                    acc[jr][jc] += wc.x * xr[jr].x + wc.y * xr[jr].y +
                                   wc.z * xr[jr].z + wc.w * xr[jr].w;
            }
        }
    }

#pragma unroll
    for (int jr = 0; jr < 4; ++jr) {
        int gr = r0 + ty * 4 + jr;
        if (gr >= N) continue;
#pragma unroll
        for (int jc = 0; jc < CPT; ++jc) {
            int col = tx + 16 * jc;
            if (col < M1) {
                if (A_BF16) ((unsigned short*)outa_)[(size_t)gr * M1 + col] = f2bf(acc[jr][jc]);
                else        ((float*)outa_)[(size_t)gr * M1 + col] = acc[jr][jc];
            } else if (col < M) {
                outb[(size_t)gr * M2 + (col - M1)] = acc[jr][jc];
            }
        }
    }

    if constexpr (AL_FOLD) {
        __syncthreads();
        float* sH = &sW[0][0];  // reuse as sH[64][68]
#pragma unroll
        for (int jr = 0; jr < 4; ++jr)
#pragma unroll
            for (int jc = 0; jc < 4; ++jc)
                sH[(ty * 4 + jr) * 68 + (tx + 16 * jc)] = acc[jr][jc];
        __syncthreads();
        int j = tid & 15, hd = j & 7;
        const float* a = (j < 8 ? as_w : ad_w) + hd * 8;
        float av[8];
#pragma unroll
        for (int c = 0; c < 8; ++c) av[c] = a[c];
#pragma unroll
        for (int q = 0; q < 4; ++q) {
            int row = (tid >> 4) + 16 * q;
            int gr = r0 + row;
            if (gr < N) {
                float sum = 0.f;
#pragma unroll
                for (int c = 0; c < 8; ++c) sum += av[c] * sH[row * 68 + hd * 8 + c];
                AL[(size_t)gr * 16 + j] = sum;
            }
        }
    }
}

// ---------------------------------------------------------------- layer-2 constant prep
__global__ void k_prep2(const float* __restrict__ W2, const float* __restrict__ as2,
                        const float* __restrict__ ad2, float* __restrict__ wt,
                        __hip_bfloat16* __restrict__ w2sw) {
    if (blockIdx.x < 96) {
        int t = blockIdx.x * 256 + threadIdx.x;
        int j = t & 7;
        int rc = t >> 3;
        int col = rc % 48, c = rc / 48;
        int k = c * 8 + j;
        int hd = k >> 6, kk = k & 63;
        float v = (col < 40) ? W2[(size_t)(hd * 40 + col) * 64 + kk] : 0.f;
        w2sw[t] = __float2bfloat16(v);
    } else {
        for (int t = threadIdx.x; t < 1024; t += 256) {
            int j = t >> 6, k = t & 63;
            int hd = j & 7;
            const float* a = (j < 8 ? as2 : ad2) + hd * 40;
            float sum = 0.f;
            for (int c = 0; c < 40; ++c) sum += a[c] * W2[(size_t)(hd * 40 + c) * 64 + k];
            wt[j * 64 + k] = sum;
        }
    }
}

// ---------------------------------------------------------------- layers 0/1: no-max softmax-aggregate, bf16 rows, paired-dim layout
__global__ __launch_bounds__(256, 8) void k_fused(
    const unsigned short* __restrict__ Hb, const float* __restrict__ AL,
    const int* __restrict__ offs, const int* __restrict__ csr,
    float* __restrict__ S, unsigned short* __restrict__ Sb, int N) {
    int wid = threadIdx.x >> 6, lane = threadIdx.x & 63;
    int n = blockIdx.x * 4 + wid;
    if (n >= N) return;
    int off = offs[n], deg = offs[n + 1] - off;
    int el = lane >> 3, hd = lane & 7;
    int dp = lane & 31, es = lane >> 5;
    int hp = dp >> 2;  // head of dims (2dp,2dp+1)
    float ald = AL[(size_t)n * 16 + 8 + hd];

    int src_c = 0; float e_c = 0.f;
    if (el < deg) {
        src_c = csr[off + el];
        float t = AL[(size_t)src_c * 16 + hd] + ald;
        e_c = __expf(t > 0.f ? t : NEG_SLOPE * t);
    }

    float s_run = 0.f, ax = 0.f, ay = 0.f;
    for (int b0 = 0; b0 < deg; b0 += 8) {
        unsigned int hv[4];
#pragma unroll
        for (int j = 0; j < 4; ++j) {
            int sj = __shfl(src_c, (2 * j + es) * 8);
            hv[j] = *(const unsigned int*)&Hb[(size_t)sj * 64 + 2 * dp];
        }
        // prefetch next block's (src, e)
        int en = b0 + 8 + el;
        int src_n = 0; float e_n = 0.f;
        if (en < deg) {
            src_n = csr[off + en];
            float t = AL[(size_t)src_n * 16 + hd] + ald;
            e_n = __expf(t > 0.f ? t : NEG_SLOPE * t);
        }

        s_run += e_c;  // lane-local; reduced after the loop
#pragma unroll
        for (int j = 0; j < 4; ++j) {
            float a = __shfl(e_c, (2 * j + es) * 8 + hp);
            unsigned int u = hv[j];
            ax += a * bf2f((unsigned short)(u & 0xffff));
            ay += a * bf2f((unsigned short)(u >> 16));
        }
        src_c = src_n; e_c = e_n;
    }
#pragma unroll
    for (int d = 8; d <= 32; d <<= 1) s_run += __shfl_xor(s_run, d);
    float sf = __shfl(s_run, hp);
    float inv = 1.0f / (sf + 1e-16f);
    ax *= inv; ay *= inv;
    ax += __shfl_xor(ax, 32);
    ay += __shfl_xor(ay, 32);
    if (es == 0) {
        float2 sk = *(const float2*)&S[(size_t)n * 64 + 2 * dp];
        float vx = sk.x + ax, vy = sk.y + ay;
        vx = vx > 0.f ? vx : expm1f(vx);
        vy = vy > 0.f ? vy : expm1f(vy);
        *(float2*)&S[(size_t)n * 64 + 2 * dp] = make_float2(vx, vy);
        if (Sb) {
            ushort2 w;
            w.x = f2bf(vx); w.y = f2bf(vy);
            *(ushort2*)&Sb[(size_t)n * 64 + 2 * dp] = w;
        }
    }
}

// ---------------------------------------------------------------- layer 2: no-max aggregate, bf16 rows, head-split -> bf16 LDS -> MFMA
__global__ __launch_bounds__(256, 8) void k_l2f(
    const unsigned short* __restrict__ Xb, const float* __restrict__ AL,
    const float* __restrict__ SK, const __hip_bfloat16* __restrict__ w2sw,
    const int* __restrict__ offs, const int* __restrict__ csr,
    float* __restrict__ out, int N) {
    __shared__ __hip_bfloat16 sA[64 * 16 * 8];  // [chunk][rot-row][8], 16 KB
    __shared__ float sC[16][48];                // 3 KB
    __shared__ float sW8[4][64];                // per-wave alpha row, 1 KB
    int wid = threadIdx.x >> 6, lane = threadIdx.x & 63;
    int el = lane >> 3, hd = lane & 7;
    int dp = lane & 31, eh = lane >> 5;

#pragma unroll 1
    for (int p = 0; p < 4; ++p) {
        int mrow = wid * 4 + p;
        int n = blockIdx.x * 16 + mrow;
        float2 acc[4];
#pragma unroll
        for (int h2 = 0; h2 < 4; ++h2) acc[h2] = make_float2(0.f, 0.f);
        if (n < N) {
            int off = offs[n], deg = offs[n + 1] - off;
            float ald = AL[(size_t)n * 16 + 8 + hd];

            int src_c = 0; float e_c = 0.f;
            if (el < deg) {
                src_c = csr[off + el];
                float t = AL[(size_t)src_c * 16 + hd] + ald;
                e_c = __expf(t > 0.f ? t : NEG_SLOPE * t);
            }

            float s_run = 0.f;
#pragma unroll 1
            for (int b0 = 0; b0 < deg; b0 += 8) {
                unsigned int xv0[4];
#pragma unroll
                for (int j = 0; j < 4; ++j) {
                    int sj = __shfl(src_c, j * 8);
                    xv0[j] = *(const unsigned int*)&Xb[(size_t)sj * 64 + 2 * dp];
                }
                // prefetch next block's (src, e)
                int en = b0 + 8 + el;
                int src_n = 0; float e_n = 0.f;
                if (en < deg) {
                    src_n = csr[off + en];
                    float t = AL[(size_t)src_n * 16 + hd] + ald;
                    e_n = __expf(t > 0.f ? t : NEG_SLOPE * t);
                }

                sW8[wid][lane] = e_c;  // stats layout [e&7]*8+hd, same-wave consume
                s_run += e_c;
#pragma unroll
                for (int j = 0; j < 4; ++j) {
                    float4 a4 = *(const float4*)&sW8[wid][j * 8 + 4 * eh];
                    float hx = bf2f((unsigned short)(xv0[j] & 0xffff));
                    float hy = bf2f((unsigned short)(xv0[j] >> 16));
                    acc[0].x += a4.x * hx; acc[0].y += a4.x * hy;
                    acc[1].x += a4.y * hx; acc[1].y += a4.y * hy;
                    acc[2].x += a4.z * hx; acc[2].y += a4.z * hy;
                    acc[3].x += a4.w * hx; acc[3].y += a4.w * hy;
                }
#pragma unroll
                for (int j = 0; j < 4; ++j) {
                    int sj = __shfl(src_c, (j + 4) * 8);
                    xv0[j] = *(const unsigned int*)&Xb[(size_t)sj * 64 + 2 * dp];
                }
#pragma unroll
                for (int j = 0; j < 4; ++j) {
                    float4 a4 = *(const float4*)&sW8[wid][(j + 4) * 8 + 4 * eh];
                    float hx = bf2f((unsigned short)(xv0[j] & 0xffff));
                    float hy = bf2f((unsigned short)(xv0[j] >> 16));
                    acc[0].x += a4.x * hx; acc[0].y += a4.x * hy;
                    acc[1].x += a4.y * hx; acc[1].y += a4.y * hy;
                    acc[2].x += a4.z * hx; acc[2].y += a4.z * hy;
                    acc[3].x += a4.w * hx; acc[3].y += a4.w * hy;
                }
                src_c = src_n; e_c = e_n;
            }
#pragma unroll
            for (int d = 8; d <= 32; d <<= 1) s_run += __shfl_xor(s_run, d);
#pragma unroll
            for (int h2 = 0; h2 < 4; ++h2) {
                float sv = __shfl(s_run, 4 * eh + h2);
                float iv = 1.0f / (sv + 1e-16f);
                acc[h2].x *= iv; acc[h2].y *= iv;
            }
        }
#pragma unroll
        for (int h2 = 0; h2 < 4; ++h2) {
            int K0 = (4 * eh + h2) * 64 + 2 * dp;
            int chunk = K0 >> 3, pos = K0 & 7;
            ushort2 w;
            w.x = f2bf(acc[h2].x); w.y = f2bf(acc[h2].y);
            *(ushort2*)&sA[chunk * 128 + ((mrow + chunk) & 15) * 8 + pos] = w;
        }
    }
    __syncthreads();

    // ---- MFMA projection: waves 0..2 each one 16-col N-tile, K=512
    if (wid < 3) {
        f32x4 cacc = {0.f, 0.f, 0.f, 0.f};
        int grp = lane >> 4;
        int r16 = lane & 15;
#pragma unroll 4
        for (int ks = 0; ks < 16; ++ks) {
            int c = ks * 4 + grp;
            short8v av = *(const short8v*)&sA[c * 128 + ((r16 + c) & 15) * 8];
            short8v bv = *(const short8v*)&w2sw[(size_t)(c * 48 + wid * 16 + r16) * 8];
            cacc = __builtin_amdgcn_mfma_f32_16x16x32_bf16(av, bv, cacc, 0, 0, 0);
        }
#pragma unroll
        for (int jj = 0; jj < 4; ++jj)
            sC[grp * 4 + jj][wid * 16 + r16] = cacc[jj];
    }
    __syncthreads();

    // ---- epilogue: + skip, log_softmax over 40 outputs
    for (int p = 0; p < 4; ++p) {
        int mrow = wid * 4 + p;
        int n = blockIdx.x * 16 + mrow;
        if (n >= N) continue;
        float val = (lane < 40) ? SK[(size_t)n * 40 + lane] + sC[mrow][lane] * 0.125f : -INFINITY;
        float mx = val;
#pragma unroll
        for (int d = 32; d; d >>= 1) mx = fmaxf(mx, __shfl_xor(mx, d));
        float ex = (lane < 40) ? __expf(val - mx) : 0.f;
        float sm = ex;
#pragma unroll
        for (int d = 32; d; d >>= 1) sm += __shfl_xor(sm, d);
        if (lane < 40) out[(size_t)n * 40 + lane] = val - mx - logf(sm);
    }
}

// ---------------------------------------------------------------- launch
extern "C" void kernel_launch(void* const* d_in, const int* in_sizes, int n_in,
                              void* d_out, int out_size, void* d_ws, size_t ws_size,
                              hipStream_t stream) {
    const float* x   = (const float*)d_in[0];
    const int*   ei  = (const int*)d_in[1];
    const float* W0  = (const float*)d_in[2];
    const float* as0 = (const float*)d_in[3];
    const float* ad0 = (const float*)d_in[4];
    const float* b0  = (const float*)d_in[5];
    const float* sW0 = (const float*)d_in[6];
    const float* sb0 = (const float*)d_in[7];
    const float* W1  = (const float*)d_in[8];
    const float* as1 = (const float*)d_in[9];
    const float* ad1 = (const float*)d_in[10];
    const float* b1  = (const float*)d_in[11];
    const float* sW1 = (const float*)d_in[12];
    const float* sb1 = (const float*)d_in[13];
    const float* W2  = (const float*)d_in[14];
    const float* as2 = (const float*)d_in[15];
    const float* ad2 = (const float*)d_in[16];
    const float* b2  = (const float*)d_in[17];
    const float* sW2 = (const float*)d_in[18];
    const float* sb2 = (const float*)d_in[19];
    float* out = (float*)d_out;

    int N = in_sizes[0] / 128;
    int E = in_sizes[1] / 2;
    int NB = (N + 63) >> BSHIFT;

    char* wsp = (char*)d_ws;
    size_t woff = 0;
    auto A = [&](size_t nbytes) -> void* {
        void* p = wsp + woff;
        woff = (woff + nbytes + 255) & ~(size_t)255;
        return p;
    };
    int* offs   = (int*)A((size_t)(N + 1) * 4);
    int* deg    = (int*)A((size_t)N * 4);
    int* bsum   = (int*)A(4096);
    int* bcnt   = (int*)A((size_t)(NB * 8 + 8) * 4);
    int* csr    = (int*)A((size_t)(E + N) * 4);
    int2* rec   = (int2*)A((size_t)NB * 8 * SLACK8 * 8);
    float* wt   = (float*)A(1024 * 4);
    __hip_bfloat16* w2sw = (__hip_bfloat16*)A(64 * 48 * 8 * 2);
    float* AL   = (float*)A((size_t)N * 16 * 4);
    float* S    = (float*)A((size_t)N * 64 * 4);
    float* T    = (float*)A((size_t)N * 64 * 4);
    unsigned short* Hb = (unsigned short*)A((size_t)N * 64 * 2);
    unsigned short* Tb = (unsigned short*)A((size_t)N * 64 * 2);
    (void)ws_size; (void)n_in; (void)out_size;

    // ---- CSR build (XCD-sliced bucketed binning)
    hipMemsetAsync(deg, 0, (size_t)N * 4, stream);
    hipMemsetAsync(bcnt, 0, (size_t)(NB * 8 + 8) * 4, stream);
    k_binA<<<(E + 255) / 256, 256, 0, stream>>>(ei, deg, bcnt, rec, E);
    int nb = (N + 1023) / 1024;
    k_scan_block<<<nb, 256, 0, stream>>>(deg, offs, bsum, N);
    k_scan_top<<<1, 256, 0, stream>>>(bsum, nb);
    k_scan_add<<<(N + 255) / 256, 256, 0, stream>>>(offs, bsum, N);
    k_binB<<<NB, 256, 0, stream>>>(rec, bcnt, offs, csr, N);

    // ---- layer-2 constants (independent)
    k_prep2<<<97, 256, 0, stream>>>(W2, as2, ad2, wt, w2sw);

    dim3 bG(16, 16);
    int gG = (N + 63) / 64;
    int gN4 = (N + 3) / 4;

    // ---- layer 0 (input x [N,128]): Hb + S(skip+biases) + AL in one GEMM
    k_gemm_dual<8, 64, 64, true, true><<<gG, bG, 0, stream>>>(
        x, W0, sW0, b0, sb0, Hb, S, as0, ad0, AL, N, 128);
    k_fused<<<gN4, 256, 0, stream>>>(Hb, AL, offs, csr, S, nullptr, N);  // S <- x1

    // ---- layer 1 (input S [N,64])
    k_gemm_dual<8, 64, 64, true, true><<<gG, bG, 0, stream>>>(
        S, W1, sW1, b1, sb1, Hb, T, as1, ad1, AL, N, 64);
    k_fused<<<gN4, 256, 0, stream>>>(Hb, AL, offs, csr, T, Tb, N);       // T <- x2 (+bf16 Tb)

    // ---- layer 2 (input T [N,64]): AL(wt part) + S(skip) in one GEMM
    k_gemm_dual<4, 16, 40, false, false><<<gG, bG, 0, stream>>>(
        T, wt, sW2, b2, sb2, AL, S, nullptr, nullptr, nullptr, N, 64);
    k_l2f<<<(N + 15) / 16, 256, 0, stream>>>(Tb, AL, S, w2sw, offs, csr, out, N);
}

// Round 14
// 485.974 us; speedup vs baseline: 1.4216x; 1.1377x over previous
//
#include <hip/hip_runtime.h>
#include <hip/hip_bf16.h>
#include <math.h>

#define HEADS 8
#define NEG_SLOPE 0.2f
#define PBITS 9
#define PBIN 512              // nodes per coarse bin
#define CHUNK 8192            // edges per k_part block
#define CAP 9216              // record capacity per bin (Poisson(8163)+8 sigma)

typedef __attribute__((ext_vector_type(8))) short short8v;
typedef __attribute__((ext_vector_type(4))) float f32x4;

__device__ __forceinline__ float bf2f(unsigned short u) {
    return __uint_as_float(((unsigned int)u) << 16);
}
__device__ __forceinline__ unsigned short f2bf(float f) {
    __hip_bfloat16 h = __float2bfloat16(f);
    union { __hip_bfloat16 h; unsigned short u; } c; c.h = h; return c.u;
}

// ---------------------------------------------------------------- CSR pass A:
// per-block LDS counting sort by coarse bin; contiguous per-bin runs written
// to globally reserved ranges -> ~1.2x write amplification instead of ~17x.
__global__ __launch_bounds__(256) void k_part(
    const int* __restrict__ ei, int* __restrict__ deg,
    int* __restrict__ binTot, int2* __restrict__ rec, int E) {
    __shared__ int hist[256];
    __shared__ int scanb[256];
    __shared__ int binStart[256];
    __shared__ int cursor[256];
    __shared__ int gbase[256];
    __shared__ int2 stag[CHUNK];   // 64 KB
    int tid = threadIdx.x;
    int base = blockIdx.x * CHUNK;

    hist[tid] = 0;
    __syncthreads();
    // phase 1: histogram + degree count
#pragma unroll 1
    for (int k = 0; k < CHUNK / 256; ++k) {
        int i = base + k * 256 + tid;
        if (i < E) {
            int d = ei[E + i];
            atomicAdd(&hist[d >> PBITS], 1);
            atomicAdd(&deg[d], 1);
        }
    }
    __syncthreads();
    // phase 2: exclusive prefix over bins
    int val = hist[tid];
    scanb[tid] = val;
    __syncthreads();
    for (int off = 1; off < 256; off <<= 1) {
        int x = 0;
        if (tid >= off) x = scanb[tid - off];
        __syncthreads();
        scanb[tid] += x;
        __syncthreads();
    }
    int excl = scanb[tid] - val;
    binStart[tid] = excl;
    cursor[tid] = excl;
    // phase 3 reservation (one atomic per non-empty bin)
    if (val > 0) gbase[tid] = atomicAdd(&binTot[tid], val);
    __syncthreads();
    int total = scanb[255];
    // phase 4: counting-sort into LDS (re-read edges, L2-hot)
#pragma unroll 1
    for (int k = 0; k < CHUNK / 256; ++k) {
        int i = base + k * 256 + tid;
        if (i < E) {
            int s = ei[i], d = ei[E + i];
            int pos = atomicAdd(&cursor[d >> PBITS], 1);
            stag[pos] = make_int2(s, d);
        }
    }
    __syncthreads();
    // phase 5: copy out bin-sorted runs (contiguous per bin)
#pragma unroll 1
    for (int idx = tid; idx < total; idx += 256) {
        int2 r = stag[idx];
        int b = r.y >> PBITS;
        int gp = gbase[b] + (idx - binStart[b]);
        if (gp < CAP) rec[(size_t)b * CAP + gp] = r;
    }
}

// deg[] holds edge counts (zeroed by memset); +1 here accounts the self-loop.
__global__ void k_scan_block(const int* __restrict__ deg, int* __restrict__ offs,
                             int* __restrict__ bsum, int N) {
    __shared__ int lds[256];
    int tid = threadIdx.x;
    int base = blockIdx.x * 1024 + tid * 4;
    int v0 = (base + 0 < N) ? deg[base + 0] + 1 : 0;
    int v1 = (base + 1 < N) ? deg[base + 1] + 1 : 0;
    int v2 = (base + 2 < N) ? deg[base + 2] + 1 : 0;
    int v3 = (base + 3 < N) ? deg[base + 3] + 1 : 0;
    int t01 = v0 + v1;
    int tot = t01 + v2 + v3;
    lds[tid] = tot;
    __syncthreads();
    for (int off = 1; off < 256; off <<= 1) {
        int x = 0;
        if (tid >= off) x = lds[tid - off];
        __syncthreads();
        lds[tid] += x;
        __syncthreads();
    }
    int ex = lds[tid] - tot;
    if (tid == 255) bsum[blockIdx.x] = lds[255];
    if (base + 0 < N) offs[base + 0] = ex;
    if (base + 1 < N) offs[base + 1] = ex + v0;
    if (base + 2 < N) offs[base + 2] = ex + t01;
    if (base + 3 < N) offs[base + 3] = ex + t01 + v2;
}

// single 256-thread block scan over nb (<=256) block sums
__global__ void k_scan_top(int* __restrict__ bsum, int nb) {
    __shared__ int lds[256];
    int tid = threadIdx.x;
    int v = (tid < nb) ? bsum[tid] : 0;
    lds[tid] = v;
    __syncthreads();
    for (int off = 1; off < 256; off <<= 1) {
        int x = 0;
        if (tid >= off) x = lds[tid - off];
        __syncthreads();
        lds[tid] += x;
        __syncthreads();
    }
    if (tid < nb) bsum[tid] = lds[tid] - v;  // exclusive
    if (tid == 0) bsum[nb] = lds[255];       // total
}

__global__ void k_scan_add(int* __restrict__ offs, const int* __restrict__ bsum, int N) {
    int i = blockIdx.x * 256 + threadIdx.x;
    if (i < N) offs[i] += bsum[i >> 10];
    if (i == 0) offs[N] = bsum[(N + 1023) >> 10];
}

// ---------------------------------------------------------------- CSR pass B:
// one block per bin; LDS-ranked writes into the bin's contiguous ~35KB csr
// window (stays hot in one L2 -> full-line writebacks only).
__global__ __launch_bounds__(256) void k_build(
    const int2* __restrict__ rec, const int* __restrict__ binTot,
    const int* __restrict__ offs, int* __restrict__ csr, int N) {
    __shared__ int loff[PBIN];
    __shared__ int lcnt[PBIN];
    int b = blockIdx.x;
    int tid = threadIdx.x;
    int n0 = b << PBITS;
    for (int q = tid; q < PBIN; q += 256) {
        lcnt[q] = 0;
        int n = n0 + q;
        if (n < N) {
            int o = offs[n];
            loff[q] = o;
            csr[o] = n;          // self-loop first
        }
    }
    __syncthreads();
    int cnt = min(binTot[b], CAP);
    const int2* basep = rec + (size_t)b * CAP;
#pragma unroll 1
    for (int i = tid; i < cnt; i += 256) {
        int2 r = basep[i];
        int l = r.y & (PBIN - 1);
        int rank = atomicAdd(&lcnt[l], 1);
        csr[loff[l] + 1 + rank] = r.x;
    }
}

// ---------------------------------------------------------------- dual GEMM (+ optional AL fold)
template <int CPT, int M1, int M2, bool AL_FOLD, bool A_BF16>
__global__ __launch_bounds__(256) void k_gemm_dual(
    const float* __restrict__ X, const float* __restrict__ Wa, const float* __restrict__ Wb,
    const float* __restrict__ bias1, const float* __restrict__ bias2,
    void* __restrict__ outa_, float* __restrict__ outb,
    const float* __restrict__ as_w, const float* __restrict__ ad_w, float* __restrict__ AL,
    int N, int K) {
    constexpr int M = M1 + M2;
    static_assert(CPT * 16 >= M, "CPT too small");
    __shared__ float sW[CPT * 16][68];
    __shared__ float sX[64][68];
    int tx = threadIdx.x, ty = threadIdx.y;
    int tid = ty * 16 + tx;
    int r0 = blockIdx.x * 64;

    float acc[4][CPT];
#pragma unroll
    for (int jc = 0; jc < CPT; ++jc) {
        int col = tx + 16 * jc;
        float b = 0.f;
        if (col >= M1 && col < M) b = bias1[col - M1] + bias2[col - M1];
#pragma unroll
        for (int jr = 0; jr < 4; ++jr) acc[jr][jc] = b;
    }

    for (int k0 = 0; k0 < K; k0 += 64) {
        __syncthreads();
        for (int idx = tid; idx < CPT * 16 * 16; idx += 256) {
            int c = idx >> 4, kq = (idx & 15) * 4;
            float4 v = make_float4(0.f, 0.f, 0.f, 0.f);
            if (c < M1) v = *(const float4*)&Wa[(size_t)c * K + k0 + kq];
            else if (c < M) v = *(const float4*)&Wb[(size_t)(c - M1) * K + k0 + kq];
            *(float4*)&sW[c][kq] = v;
        }
        for (int idx = tid; idx < 64 * 16; idx += 256) {
            int r = idx >> 4, kq = (idx & 15) * 4;
            int gr = r0 + r;
            float4 v = make_float4(0.f, 0.f, 0.f, 0.f);
            if (gr < N) v = *(const float4*)&X[(size_t)gr * K + k0 + kq];
            *(float4*)&sX[r][kq] = v;
        }
        __syncthreads();

        for (int k = 0; k < 64; k += 4) {
            float4 xr[4];
#pragma unroll
            for (int jr = 0; jr < 4; ++jr) xr[jr] = *(const float4*)&sX[ty * 4 + jr][k];
#pragma unroll
            for (int jc = 0; jc < CPT; ++jc) {
                float4 wc = *(const float4*)&sW[tx + 16 * jc][k];
#pragma unroll
                for (int jr = 0; jr < 4; ++jr)
                    acc[jr][jc] += wc.x * xr[jr].x + wc.y * xr[jr].y +
                                   wc.z * xr[jr].z + wc.w * xr[jr].w;
            }
        }
    }

#pragma unroll
    for (int jr = 0; jr < 4; ++jr) {
        int gr = r0 + ty * 4 + jr;
        if (gr >= N) continue;
#pragma unroll
        for (int jc = 0; jc < CPT; ++jc) {
            int col = tx + 16 * jc;
            if (col < M1) {
                if (A_BF16) ((unsigned short*)outa_)[(size_t)gr * M1 + col] = f2bf(acc[jr][jc]);
                else        ((float*)outa_)[(size_t)gr * M1 + col] = acc[jr][jc];
            } else if (col < M) {
                outb[(size_t)gr * M2 + (col - M1)] = acc[jr][jc];
            }
        }
    }

    if constexpr (AL_FOLD) {
        __syncthreads();
        float* sH = &sW[0][0];  // reuse as sH[64][68]
#pragma unroll
        for (int jr = 0; jr < 4; ++jr)
#pragma unroll
            for (int jc = 0; jc < 4; ++jc)
                sH[(ty * 4 + jr) * 68 + (tx + 16 * jc)] = acc[jr][jc];
        __syncthreads();
        int j = tid & 15, hd = j & 7;
        const float* a = (j < 8 ? as_w : ad_w) + hd * 8;
        float av[8];
#pragma unroll
        for (int c = 0; c < 8; ++c) av[c] = a[c];
#pragma unroll
        for (int q = 0; q < 4; ++q) {
            int row = (tid >> 4) + 16 * q;
            int gr = r0 + row;
            if (gr < N) {
                float sum = 0.f;
#pragma unroll
                for (int c = 0; c < 8; ++c) sum += av[c] * sH[row * 68 + hd * 8 + c];
                AL[(size_t)gr * 16 + j] = sum;
            }
        }
    }
}

// ---------------------------------------------------------------- layer-2 constant prep
__global__ void k_prep2(const float* __restrict__ W2, const float* __restrict__ as2,
                        const float* __restrict__ ad2, float* __restrict__ wt,
                        __hip_bfloat16* __restrict__ w2sw) {
    if (blockIdx.x < 96) {
        int t = blockIdx.x * 256 + threadIdx.x;
        int j = t & 7;
        int rc = t >> 3;
        int col = rc % 48, c = rc / 48;
        int k = c * 8 + j;
        int hd = k >> 6, kk = k & 63;
        float v = (col < 40) ? W2[(size_t)(hd * 40 + col) * 64 + kk] : 0.f;
        w2sw[t] = __float2bfloat16(v);
    } else {
        for (int t = threadIdx.x; t < 1024; t += 256) {
            int j = t >> 6, k = t & 63;
            int hd = j & 7;
            const float* a = (j < 8 ? as2 : ad2) + hd * 40;
            float sum = 0.f;
            for (int c = 0; c < 40; ++c) sum += a[c] * W2[(size_t)(hd * 40 + c) * 64 + k];
            wt[j * 64 + k] = sum;
        }
    }
}

// ---------------------------------------------------------------- layers 0/1: no-max softmax-aggregate, bf16 rows, paired-dim layout
__global__ __launch_bounds__(256, 8) void k_fused(
    const unsigned short* __restrict__ Hb, const float* __restrict__ AL,
    const int* __restrict__ offs, const int* __restrict__ csr,
    float* __restrict__ S, unsigned short* __restrict__ Sb, int N) {
    int wid = threadIdx.x >> 6, lane = threadIdx.x & 63;
    int n = blockIdx.x * 4 + wid;
    if (n >= N) return;
    int off = offs[n], deg = offs[n + 1] - off;
    int el = lane >> 3, hd = lane & 7;
    int dp = lane & 31, es = lane >> 5;
    int hp = dp >> 2;  // head of dims (2dp,2dp+1)
    float ald = AL[(size_t)n * 16 + 8 + hd];

    int src_c = 0; float e_c = 0.f;
    if (el < deg) {
        src_c = csr[off + el];
        float t = AL[(size_t)src_c * 16 + hd] + ald;
        e_c = __expf(t > 0.f ? t : NEG_SLOPE * t);
    }

    float s_run = 0.f, ax = 0.f, ay = 0.f;
    for (int b0 = 0; b0 < deg; b0 += 8) {
        unsigned int hv[4];
#pragma unroll
        for (int j = 0; j < 4; ++j) {
            int sj = __shfl(src_c, (2 * j + es) * 8);
            hv[j] = *(const unsigned int*)&Hb[(size_t)sj * 64 + 2 * dp];
        }
        // prefetch next block's (src, e)
        int en = b0 + 8 + el;
        int src_n = 0; float e_n = 0.f;
        if (en < deg) {
            src_n = csr[off + en];
            float t = AL[(size_t)src_n * 16 + hd] + ald;
            e_n = __expf(t > 0.f ? t : NEG_SLOPE * t);
        }

        s_run += e_c;  // lane-local; reduced after the loop
#pragma unroll
        for (int j = 0; j < 4; ++j) {
            float a = __shfl(e_c, (2 * j + es) * 8 + hp);
            unsigned int u = hv[j];
            ax += a * bf2f((unsigned short)(u & 0xffff));
            ay += a * bf2f((unsigned short)(u >> 16));
        }
        src_c = src_n; e_c = e_n;
    }
#pragma unroll
    for (int d = 8; d <= 32; d <<= 1) s_run += __shfl_xor(s_run, d);
    float sf = __shfl(s_run, hp);
    float inv = 1.0f / (sf + 1e-16f);
    ax *= inv; ay *= inv;
    ax += __shfl_xor(ax, 32);
    ay += __shfl_xor(ay, 32);
    if (es == 0) {
        float2 sk = *(const float2*)&S[(size_t)n * 64 + 2 * dp];
        float vx = sk.x + ax, vy = sk.y + ay;
        vx = vx > 0.f ? vx : expm1f(vx);
        vy = vy > 0.f ? vy : expm1f(vy);
        *(float2*)&S[(size_t)n * 64 + 2 * dp] = make_float2(vx, vy);
        if (Sb) {
            ushort2 w;
            w.x = f2bf(vx); w.y = f2bf(vy);
            *(ushort2*)&Sb[(size_t)n * 64 + 2 * dp] = w;
        }
    }
}

// ---------------------------------------------------------------- layer 2: no-max aggregate, bf16 rows, head-split -> bf16 LDS -> MFMA
__global__ __launch_bounds__(256, 8) void k_l2f(
    const unsigned short* __restrict__ Xb, const float* __restrict__ AL,
    const float* __restrict__ SK, const __hip_bfloat16* __restrict__ w2sw,
    const int* __restrict__ offs, const int* __restrict__ csr,
    float* __restrict__ out, int N) {
    __shared__ __hip_bfloat16 sA[64 * 16 * 8];  // [chunk][rot-row][8], 16 KB
    __shared__ float sC[16][48];                // 3 KB
    __shared__ float sW8[4][64];                // per-wave alpha row, 1 KB
    int wid = threadIdx.x >> 6, lane = threadIdx.x & 63;
    int el = lane >> 3, hd = lane & 7;
    int dp = lane & 31, eh = lane >> 5;

#pragma unroll 1
    for (int p = 0; p < 4; ++p) {
        int mrow = wid * 4 + p;
        int n = blockIdx.x * 16 + mrow;
        float2 acc[4];
#pragma unroll
        for (int h2 = 0; h2 < 4; ++h2) acc[h2] = make_float2(0.f, 0.f);
        if (n < N) {
            int off = offs[n], deg = offs[n + 1] - off;
            float ald = AL[(size_t)n * 16 + 8 + hd];

            int src_c = 0; float e_c = 0.f;
            if (el < deg) {
                src_c = csr[off + el];
                float t = AL[(size_t)src_c * 16 + hd] + ald;
                e_c = __expf(t > 0.f ? t : NEG_SLOPE * t);
            }

            float s_run = 0.f;
#pragma unroll 1
            for (int b0 = 0; b0 < deg; b0 += 8) {
                unsigned int xv0[4];
#pragma unroll
                for (int j = 0; j < 4; ++j) {
                    int sj = __shfl(src_c, j * 8);
                    xv0[j] = *(const unsigned int*)&Xb[(size_t)sj * 64 + 2 * dp];
                }
                // prefetch next block's (src, e)
                int en = b0 + 8 + el;
                int src_n = 0; float e_n = 0.f;
                if (en < deg) {
                    src_n = csr[off + en];
                    float t = AL[(size_t)src_n * 16 + hd] + ald;
                    e_n = __expf(t > 0.f ? t : NEG_SLOPE * t);
                }

                sW8[wid][lane] = e_c;  // stats layout [e&7]*8+hd, same-wave consume
                s_run += e_c;
#pragma unroll
                for (int j = 0; j < 4; ++j) {
                    float4 a4 = *(const float4*)&sW8[wid][j * 8 + 4 * eh];
                    float hx = bf2f((unsigned short)(xv0[j] & 0xffff));
                    float hy = bf2f((unsigned short)(xv0[j] >> 16));
                    acc[0].x += a4.x * hx; acc[0].y += a4.x * hy;
                    acc[1].x += a4.y * hx; acc[1].y += a4.y * hy;
                    acc[2].x += a4.z * hx; acc[2].y += a4.z * hy;
                    acc[3].x += a4.w * hx; acc[3].y += a4.w * hy;
                }
#pragma unroll
                for (int j = 0; j < 4; ++j) {
                    int sj = __shfl(src_c, (j + 4) * 8);
                    xv0[j] = *(const unsigned int*)&Xb[(size_t)sj * 64 + 2 * dp];
                }
#pragma unroll
                for (int j = 0; j < 4; ++j) {
                    float4 a4 = *(const float4*)&sW8[wid][(j + 4) * 8 + 4 * eh];
                    float hx = bf2f((unsigned short)(xv0[j] & 0xffff));
                    float hy = bf2f((unsigned short)(xv0[j] >> 16));
                    acc[0].x += a4.x * hx; acc[0].y += a4.x * hy;
                    acc[1].x += a4.y * hx; acc[1].y += a4.y * hy;
                    acc[2].x += a4.z * hx; acc[2].y += a4.z * hy;
                    acc[3].x += a4.w * hx; acc[3].y += a4.w * hy;
                }
                src_c = src_n; e_c = e_n;
            }
#pragma unroll
            for (int d = 8; d <= 32; d <<= 1) s_run += __shfl_xor(s_run, d);
#pragma unroll
            for (int h2 = 0; h2 < 4; ++h2) {
                float sv = __shfl(s_run, 4 * eh + h2);
                float iv = 1.0f / (sv + 1e-16f);
                acc[h2].x *= iv; acc[h2].y *= iv;
            }
        }
#pragma unroll
        for (int h2 = 0; h2 < 4; ++h2) {
            int K0 = (4 * eh + h2) * 64 + 2 * dp;
            int chunk = K0 >> 3, pos = K0 & 7;
            ushort2 w;
            w.x = f2bf(acc[h2].x); w.y = f2bf(acc[h2].y);
            *(ushort2*)&sA[chunk * 128 + ((mrow + chunk) & 15) * 8 + pos] = w;
        }
    }
    __syncthreads();

    // ---- MFMA projection: waves 0..2 each one 16-col N-tile, K=512
    if (wid < 3) {
        f32x4 cacc = {0.f, 0.f, 0.f, 0.f};
        int grp = lane >> 4;
        int r16 = lane & 15;
#pragma unroll 4
        for (int ks = 0; ks < 16; ++ks) {
            int c = ks * 4 + grp;
            short8v av = *(const short8v*)&sA[c * 128 + ((r16 + c) & 15) * 8];
            short8v bv = *(const short8v*)&w2sw[(size_t)(c * 48 + wid * 16 + r16) * 8];
            cacc = __builtin_amdgcn_mfma_f32_16x16x32_bf16(av, bv, cacc, 0, 0, 0);
        }
#pragma unroll
        for (int jj = 0; jj < 4; ++jj)
            sC[grp * 4 + jj][wid * 16 + r16] = cacc[jj];
    }
    __syncthreads();

    // ---- epilogue: + skip, log_softmax over 40 outputs
    for (int p = 0; p < 4; ++p) {
        int mrow = wid * 4 + p;
        int n = blockIdx.x * 16 + mrow;
        if (n >= N) continue;
        float val = (lane < 40) ? SK[(size_t)n * 40 + lane] + sC[mrow][lane] * 0.125f : -INFINITY;
        float mx = val;
#pragma unroll
        for (int d = 32; d; d >>= 1) mx = fmaxf(mx, __shfl_xor(mx, d));
        float ex = (lane < 40) ? __expf(val - mx) : 0.f;
        float sm = ex;
#pragma unroll
        for (int d = 32; d; d >>= 1) sm += __shfl_xor(sm, d);
        if (lane < 40) out[(size_t)n * 40 + lane] = val - mx - logf(sm);
    }
}

// ---------------------------------------------------------------- launch
extern "C" void kernel_launch(void* const* d_in, const int* in_sizes, int n_in,
                              void* d_out, int out_size, void* d_ws, size_t ws_size,
                              hipStream_t stream) {
    const float* x   = (const float*)d_in[0];
    const int*   ei  = (const int*)d_in[1];
    const float* W0  = (const float*)d_in[2];
    const float* as0 = (const float*)d_in[3];
    const float* ad0 = (const float*)d_in[4];
    const float* b0  = (const float*)d_in[5];
    const float* sW0 = (const float*)d_in[6];
    const float* sb0 = (const float*)d_in[7];
    const float* W1  = (const float*)d_in[8];
    const float* as1 = (const float*)d_in[9];
    const float* ad1 = (const float*)d_in[10];
    const float* b1  = (const float*)d_in[11];
    const float* sW1 = (const float*)d_in[12];
    const float* sb1 = (const float*)d_in[13];
    const float* W2  = (const float*)d_in[14];
    const float* as2 = (const float*)d_in[15];
    const float* ad2 = (const float*)d_in[16];
    const float* b2  = (const float*)d_in[17];
    const float* sW2 = (const float*)d_in[18];
    const float* sb2 = (const float*)d_in[19];
    float* out = (float*)d_out;

    int N = in_sizes[0] / 128;
    int E = in_sizes[1] / 2;
    int NBIN = (N + PBIN - 1) >> PBITS;

    char* wsp = (char*)d_ws;
    size_t woff = 0;
    auto A = [&](size_t nbytes) -> void* {
        void* p = wsp + woff;
        woff = (woff + nbytes + 255) & ~(size_t)255;
        return p;
    };
    int* offs   = (int*)A((size_t)(N + 1) * 4);
    int* deg    = (int*)A((size_t)N * 4);
    int* bsum   = (int*)A(4096);
    int* binTot = (int*)A((size_t)(NBIN + 1) * 4);
    int* csr    = (int*)A((size_t)(E + N) * 4);
    int2* rec   = (int2*)A((size_t)NBIN * CAP * 8);
    float* wt   = (float*)A(1024 * 4);
    __hip_bfloat16* w2sw = (__hip_bfloat16*)A(64 * 48 * 8 * 2);
    float* AL   = (float*)A((size_t)N * 16 * 4);
    float* S    = (float*)A((size_t)N * 64 * 4);
    float* T    = (float*)A((size_t)N * 64 * 4);
    unsigned short* Hb = (unsigned short*)A((size_t)N * 64 * 2);
    unsigned short* Tb = (unsigned short*)A((size_t)N * 64 * 2);
    (void)ws_size; (void)n_in; (void)out_size;

    // ---- CSR build (LDS-staged counting-sort partition)
    hipMemsetAsync(deg, 0, (size_t)N * 4, stream);
    hipMemsetAsync(binTot, 0, (size_t)(NBIN + 1) * 4, stream);
    int gPart = (E + CHUNK - 1) / CHUNK;
    k_part<<<gPart, 256, 0, stream>>>(ei, deg, binTot, rec, E);
    int nb = (N + 1023) / 1024;
    k_scan_block<<<nb, 256, 0, stream>>>(deg, offs, bsum, N);
    k_scan_top<<<1, 256, 0, stream>>>(bsum, nb);
    k_scan_add<<<(N + 255) / 256, 256, 0, stream>>>(offs, bsum, N);
    k_build<<<NBIN, 256, 0, stream>>>(rec, binTot, offs, csr, N);

    // ---- layer-2 constants (independent)
    k_prep2<<<97, 256, 0, stream>>>(W2, as2, ad2, wt, w2sw);

    dim3 bG(16, 16);
    int gG = (N + 63) / 64;
    int gN4 = (N + 3) / 4;

    // ---- layer 0 (input x [N,128]): Hb + S(skip+biases) + AL in one GEMM
    k_gemm_dual<8, 64, 64, true, true><<<gG, bG, 0, stream>>>(
        x, W0, sW0, b0, sb0, Hb, S, as0, ad0, AL, N, 128);
    k_fused<<<gN4, 256, 0, stream>>>(Hb, AL, offs, csr, S, nullptr, N);  // S <- x1

    // ---- layer 1 (input S [N,64])
    k_gemm_dual<8, 64, 64, true, true><<<gG, bG, 0, stream>>>(
        S, W1, sW1, b1, sb1, Hb, T, as1, ad1, AL, N, 64);
    k_fused<<<gN4, 256, 0, stream>>>(Hb, AL, offs, csr, T, Tb, N);       // T <- x2 (+bf16 Tb)

    // ---- layer 2 (input T [N,64]): AL(wt part) + S(skip) in one GEMM
    k_gemm_dual<4, 16, 40, false, false><<<gG, bG, 0, stream>>>(
        T, wt, sW2, b2, sb2, AL, S, nullptr, nullptr, nullptr, N, 64);
    k_l2f<<<(N + 15) / 16, 256, 0, stream>>>(Tb, AL, S, w2sw, offs, csr, out, N);
}

// Round 15
// 484.151 us; speedup vs baseline: 1.4269x; 1.0038x over previous
//
#include <hip/hip_runtime.h>
#include <hip/hip_bf16.h>
#include <math.h>

#define HEADS 8
#define NEG_SLOPE 0.2f
#define PBITS 9
#define PBIN 512              // nodes per coarse bin
#define CHUNK 8192            // edges per k_part block
#define CAP 9216              // record capacity per bin (Poisson(8163)+8 sigma)

typedef __attribute__((ext_vector_type(8))) short short8v;
typedef __attribute__((ext_vector_type(4))) float f32x4;

__device__ __forceinline__ float bf2f(unsigned short u) {
    return __uint_as_float(((unsigned int)u) << 16);
}
__device__ __forceinline__ unsigned short f2bf(float f) {
    __hip_bfloat16 h = __float2bfloat16(f);
    union { __hip_bfloat16 h; unsigned short u; } c; c.h = h; return c.u;
}

// ---------------------------------------------------------------- CSR pass A:
// per-block LDS counting sort by coarse bin; contiguous per-bin runs written
// to globally reserved ranges -> ~1.2x write amplification instead of ~17x.
__global__ __launch_bounds__(256) void k_part(
    const int* __restrict__ ei, int* __restrict__ deg,
    int* __restrict__ binTot, int2* __restrict__ rec, int E) {
    __shared__ int hist[256];
    __shared__ int scanb[256];
    __shared__ int binStart[256];
    __shared__ int cursor[256];
    __shared__ int gbase[256];
    __shared__ int2 stag[CHUNK];   // 64 KB
    int tid = threadIdx.x;
    int base = blockIdx.x * CHUNK;

    hist[tid] = 0;
    __syncthreads();
#pragma unroll 1
    for (int k = 0; k < CHUNK / 256; ++k) {
        int i = base + k * 256 + tid;
        if (i < E) {
            int d = ei[E + i];
            atomicAdd(&hist[d >> PBITS], 1);
            atomicAdd(&deg[d], 1);
        }
    }
    __syncthreads();
    int val = hist[tid];
    scanb[tid] = val;
    __syncthreads();
    for (int off = 1; off < 256; off <<= 1) {
        int x = 0;
        if (tid >= off) x = scanb[tid - off];
        __syncthreads();
        scanb[tid] += x;
        __syncthreads();
    }
    int excl = scanb[tid] - val;
    binStart[tid] = excl;
    cursor[tid] = excl;
    if (val > 0) gbase[tid] = atomicAdd(&binTot[tid], val);
    __syncthreads();
    int total = scanb[255];
#pragma unroll 1
    for (int k = 0; k < CHUNK / 256; ++k) {
        int i = base + k * 256 + tid;
        if (i < E) {
            int s = ei[i], d = ei[E + i];
            int pos = atomicAdd(&cursor[d >> PBITS], 1);
            stag[pos] = make_int2(s, d);
        }
    }
    __syncthreads();
#pragma unroll 1
    for (int idx = tid; idx < total; idx += 256) {
        int2 r = stag[idx];
        int b = r.y >> PBITS;
        int gp = gbase[b] + (idx - binStart[b]);
        if (gp < CAP) rec[(size_t)b * CAP + gp] = r;
    }
}

// deg[] holds edge counts (zeroed by memset); +1 here accounts the self-loop.
__global__ void k_scan_block(const int* __restrict__ deg, int* __restrict__ offs,
                             int* __restrict__ bsum, int N) {
    __shared__ int lds[256];
    int tid = threadIdx.x;
    int base = blockIdx.x * 1024 + tid * 4;
    int v0 = (base + 0 < N) ? deg[base + 0] + 1 : 0;
    int v1 = (base + 1 < N) ? deg[base + 1] + 1 : 0;
    int v2 = (base + 2 < N) ? deg[base + 2] + 1 : 0;
    int v3 = (base + 3 < N) ? deg[base + 3] + 1 : 0;
    int t01 = v0 + v1;
    int tot = t01 + v2 + v3;
    lds[tid] = tot;
    __syncthreads();
    for (int off = 1; off < 256; off <<= 1) {
        int x = 0;
        if (tid >= off) x = lds[tid - off];
        __syncthreads();
        lds[tid] += x;
        __syncthreads();
    }
    int ex = lds[tid] - tot;
    if (tid == 255) bsum[blockIdx.x] = lds[255];
    if (base + 0 < N) offs[base + 0] = ex;
    if (base + 1 < N) offs[base + 1] = ex + v0;
    if (base + 2 < N) offs[base + 2] = ex + t01;
    if (base + 3 < N) offs[base + 3] = ex + t01 + v2;
}

// single 256-thread block scan over nb (<=256) block sums
__global__ void k_scan_top(int* __restrict__ bsum, int nb) {
    __shared__ int lds[256];
    int tid = threadIdx.x;
    int v = (tid < nb) ? bsum[tid] : 0;
    lds[tid] = v;
    __syncthreads();
    for (int off = 1; off < 256; off <<= 1) {
        int x = 0;
        if (tid >= off) x = lds[tid - off];
        __syncthreads();
        lds[tid] += x;
        __syncthreads();
    }
    if (tid < nb) bsum[tid] = lds[tid] - v;  // exclusive
    if (tid == 0) bsum[nb] = lds[255];       // total
}

__global__ void k_scan_add(int* __restrict__ offs, const int* __restrict__ bsum, int N) {
    int i = blockIdx.x * 256 + threadIdx.x;
    if (i < N) offs[i] += bsum[i >> 10];
    if (i == 0) offs[N] = bsum[(N + 1023) >> 10];
}

// ---------------------------------------------------------------- CSR pass B
__global__ __launch_bounds__(256) void k_build(
    const int2* __restrict__ rec, const int* __restrict__ binTot,
    const int* __restrict__ offs, int* __restrict__ csr, int N) {
    __shared__ int loff[PBIN];
    __shared__ int lcnt[PBIN];
    int b = blockIdx.x;
    int tid = threadIdx.x;
    int n0 = b << PBITS;
    for (int q = tid; q < PBIN; q += 256) {
        lcnt[q] = 0;
        int n = n0 + q;
        if (n < N) {
            int o = offs[n];
            loff[q] = o;
            csr[o] = n;          // self-loop first
        }
    }
    __syncthreads();
    int cnt = min(binTot[b], CAP);
    const int2* basep = rec + (size_t)b * CAP;
#pragma unroll 1
    for (int i = tid; i < cnt; i += 256) {
        int2 r = basep[i];
        int l = r.y & (PBIN - 1);
        int rank = atomicAdd(&lcnt[l], 1);
        csr[loff[l] + 1 + rank] = r.x;
    }
}

// ---------------------------------------------------------------- dual GEMM (+ optional AL fold, AL in bf16)
template <int CPT, int M1, int M2, bool AL_FOLD, bool A_BF16>
__global__ __launch_bounds__(256) void k_gemm_dual(
    const float* __restrict__ X, const float* __restrict__ Wa, const float* __restrict__ Wb,
    const float* __restrict__ bias1, const float* __restrict__ bias2,
    void* __restrict__ outa_, float* __restrict__ outb,
    const float* __restrict__ as_w, const float* __restrict__ ad_w,
    unsigned short* __restrict__ AL, int N, int K) {
    constexpr int M = M1 + M2;
    static_assert(CPT * 16 >= M, "CPT too small");
    __shared__ float sW[CPT * 16][68];
    __shared__ float sX[64][68];
    int tx = threadIdx.x, ty = threadIdx.y;
    int tid = ty * 16 + tx;
    int r0 = blockIdx.x * 64;

    float acc[4][CPT];
#pragma unroll
    for (int jc = 0; jc < CPT; ++jc) {
        int col = tx + 16 * jc;
        float b = 0.f;
        if (col >= M1 && col < M) b = bias1[col - M1] + bias2[col - M1];
#pragma unroll
        for (int jr = 0; jr < 4; ++jr) acc[jr][jc] = b;
    }

    for (int k0 = 0; k0 < K; k0 += 64) {
        __syncthreads();
        for (int idx = tid; idx < CPT * 16 * 16; idx += 256) {
            int c = idx >> 4, kq = (idx & 15) * 4;
            float4 v = make_float4(0.f, 0.f, 0.f, 0.f);
            if (c < M1) v = *(const float4*)&Wa[(size_t)c * K + k0 + kq];
            else if (c < M) v = *(const float4*)&Wb[(size_t)(c - M1) * K + k0 + kq];
            *(float4*)&sW[c][kq] = v;
        }
        for (int idx = tid; idx < 64 * 16; idx += 256) {
            int r = idx >> 4, kq = (idx & 15) * 4;
            int gr = r0 + r;
            float4 v = make_float4(0.f, 0.f, 0.f, 0.f);
            if (gr < N) v = *(const float4*)&X[(size_t)gr * K + k0 + kq];
            *(float4*)&sX[r][kq] = v;
        }
        __syncthreads();

        for (int k = 0; k < 64; k += 4) {
            float4 xr[4];
#pragma unroll
            for (int jr = 0; jr < 4; ++jr) xr[jr] = *(const float4*)&sX[ty * 4 + jr][k];
#pragma unroll
            for (int jc = 0; jc < CPT; ++jc) {
                float4 wc = *(const float4*)&sW[tx + 16 * jc][k];
#pragma unroll
                for (int jr = 0; jr < 4; ++jr)
                    acc[jr][jc] += wc.x * xr[jr].x + wc.y * xr[jr].y +
                                   wc.z * xr[jr].z + wc.w * xr[jr].w;
            }
        }
    }

#pragma unroll
    for (int jr = 0; jr < 4; ++jr) {
        int gr = r0 + ty * 4 + jr;
        if (gr >= N) continue;
#pragma unroll
        for (int jc = 0; jc < CPT; ++jc) {
            int col = tx + 16 * jc;
            if (col < M1) {
                if (A_BF16) ((unsigned short*)outa_)[(size_t)gr * M1 + col] = f2bf(acc[jr][jc]);
                else        ((float*)outa_)[(size_t)gr * M1 + col] = acc[jr][jc];
            } else if (col < M) {
                outb[(size_t)gr * M2 + (col - M1)] = acc[jr][jc];
            }
        }
    }

    if constexpr (AL_FOLD) {
        __syncthreads();
        float* sH = &sW[0][0];  // reuse as sH[64][68]
#pragma unroll
        for (int jr = 0; jr < 4; ++jr)
#pragma unroll
            for (int jc = 0; jc < 4; ++jc)
                sH[(ty * 4 + jr) * 68 + (tx + 16 * jc)] = acc[jr][jc];
        __syncthreads();
        int j = tid & 15, hd = j & 7;
        const float* a = (j < 8 ? as_w : ad_w) + hd * 8;
        float av[8];
#pragma unroll
        for (int c = 0; c < 8; ++c) av[c] = a[c];
#pragma unroll
        for (int q = 0; q < 4; ++q) {
            int row = (tid >> 4) + 16 * q;
            int gr = r0 + row;
            if (gr < N) {
                float sum = 0.f;
#pragma unroll
                for (int c = 0; c < 8; ++c) sum += av[c] * sH[row * 68 + hd * 8 + c];
                AL[(size_t)gr * 16 + j] = f2bf(sum);
            }
        }
    }
}

// ---------------------------------------------------------------- layer-2 constant prep
__global__ void k_prep2(const float* __restrict__ W2, const float* __restrict__ as2,
                        const float* __restrict__ ad2, float* __restrict__ wt,
                        __hip_bfloat16* __restrict__ w2sw) {
    if (blockIdx.x < 96) {
        int t = blockIdx.x * 256 + threadIdx.x;
        int j = t & 7;
        int rc = t >> 3;
        int col = rc % 48, c = rc / 48;
        int k = c * 8 + j;
        int hd = k >> 6, kk = k & 63;
        float v = (col < 40) ? W2[(size_t)(hd * 40 + col) * 64 + kk] : 0.f;
        w2sw[t] = __float2bfloat16(v);
    } else {
        for (int t = threadIdx.x; t < 1024; t += 256) {
            int j = t >> 6, k = t & 63;
            int hd = j & 7;
            const float* a = (j < 8 ? as2 : ad2) + hd * 40;
            float sum = 0.f;
            for (int c = 0; c < 40; ++c) sum += a[c] * W2[(size_t)(hd * 40 + c) * 64 + k];
            wt[j * 64 + k] = sum;
        }
    }
}

// ---------------------------------------------------------------- layers 0/1: no-max softmax-aggregate, bf16 rows + bf16 AL
__global__ __launch_bounds__(256, 8) void k_fused(
    const unsigned short* __restrict__ Hb, const unsigned short* __restrict__ AL,
    const int* __restrict__ offs, const int* __restrict__ csr,
    float* __restrict__ S, unsigned short* __restrict__ Sb, int N) {
    int wid = threadIdx.x >> 6, lane = threadIdx.x & 63;
    int n = blockIdx.x * 4 + wid;
    if (n >= N) return;
    int off = offs[n], deg = offs[n + 1] - off;
    int el = lane >> 3, hd = lane & 7;
    int dp = lane & 31, es = lane >> 5;
    int hp = dp >> 2;  // head of dims (2dp,2dp+1)
    float ald = bf2f(AL[(size_t)n * 16 + 8 + hd]);

    int src_c = 0; float e_c = 0.f;
    if (el < deg) {
        src_c = csr[off + el];
        float t = bf2f(AL[(size_t)src_c * 16 + hd]) + ald;
        e_c = __expf(t > 0.f ? t : NEG_SLOPE * t);
    }

    float s_run = 0.f, ax = 0.f, ay = 0.f;
    for (int b0 = 0; b0 < deg; b0 += 8) {
        unsigned int hv[4];
#pragma unroll
        for (int j = 0; j < 4; ++j) {
            int sj = __shfl(src_c, (2 * j + es) * 8);
            hv[j] = *(const unsigned int*)&Hb[(size_t)sj * 64 + 2 * dp];
        }
        // prefetch next block's (src, e)
        int en = b0 + 8 + el;
        int src_n = 0; float e_n = 0.f;
        if (en < deg) {
            src_n = csr[off + en];
            float t = bf2f(AL[(size_t)src_n * 16 + hd]) + ald;
            e_n = __expf(t > 0.f ? t : NEG_SLOPE * t);
        }

        s_run += e_c;  // lane-local; reduced after the loop
#pragma unroll
        for (int j = 0; j < 4; ++j) {
            float a = __shfl(e_c, (2 * j + es) * 8 + hp);
            unsigned int u = hv[j];
            ax += a * bf2f((unsigned short)(u & 0xffff));
            ay += a * bf2f((unsigned short)(u >> 16));
        }
        src_c = src_n; e_c = e_n;
    }
#pragma unroll
    for (int d = 8; d <= 32; d <<= 1) s_run += __shfl_xor(s_run, d);
    float sf = __shfl(s_run, hp);
    float inv = 1.0f / (sf + 1e-16f);
    ax *= inv; ay *= inv;
    ax += __shfl_xor(ax, 32);
    ay += __shfl_xor(ay, 32);
    if (es == 0) {
        float2 sk = *(const float2*)&S[(size_t)n * 64 + 2 * dp];
        float vx = sk.x + ax, vy = sk.y + ay;
        vx = vx > 0.f ? vx : expm1f(vx);
        vy = vy > 0.f ? vy : expm1f(vy);
        *(float2*)&S[(size_t)n * 64 + 2 * dp] = make_float2(vx, vy);
        if (Sb) {
            ushort2 w;
            w.x = f2bf(vx); w.y = f2bf(vy);
            *(ushort2*)&Sb[(size_t)n * 64 + 2 * dp] = w;
        }
    }
}

// ---------------------------------------------------------------- layer 2: no-max aggregate, pk_fma accumulate, bf16 rows + bf16 AL
__global__ __launch_bounds__(256, 8) void k_l2f(
    const unsigned short* __restrict__ Xb, const unsigned short* __restrict__ AL,
    const float* __restrict__ SK, const __hip_bfloat16* __restrict__ w2sw,
    const int* __restrict__ offs, const int* __restrict__ csr,
    float* __restrict__ out, int N) {
    __shared__ __hip_bfloat16 sA[64 * 16 * 8];  // [chunk][rot-row][8], 16 KB
    __shared__ float sC[16][48];                // 3 KB
    __shared__ float sW8[4][64];                // per-wave alpha row, 1 KB
    int wid = threadIdx.x >> 6, lane = threadIdx.x & 63;
    int el = lane >> 3, hd = lane & 7;
    int dp = lane & 31, eh = lane >> 5;

#pragma unroll 1
    for (int p = 0; p < 4; ++p) {
        int mrow = wid * 4 + p;
        int n = blockIdx.x * 16 + mrow;
        float2 acc0 = make_float2(0.f, 0.f), acc1 = make_float2(0.f, 0.f);
        float2 acc2 = make_float2(0.f, 0.f), acc3 = make_float2(0.f, 0.f);
        float s_run = 0.f;
        bool live = (n < N);
        if (live) {
            int off = offs[n], deg = offs[n + 1] - off;
            float ald = bf2f(AL[(size_t)n * 16 + 8 + hd]);

            int src_c = 0; float e_c = 0.f;
            if (el < deg) {
                src_c = csr[off + el];
                float t = bf2f(AL[(size_t)src_c * 16 + hd]) + ald;
                e_c = __expf(t > 0.f ? t : NEG_SLOPE * t);
            }

#pragma unroll 1
            for (int b0 = 0; b0 < deg; b0 += 8) {
                unsigned int xv0[4];
#pragma unroll
                for (int j = 0; j < 4; ++j) {
                    int sj = __shfl(src_c, j * 8);
                    xv0[j] = *(const unsigned int*)&Xb[(size_t)sj * 64 + 2 * dp];
                }
                // prefetch next block's (src, e)
                int en = b0 + 8 + el;
                int src_n = 0; float e_n = 0.f;
                if (en < deg) {
                    src_n = csr[off + en];
                    float t = bf2f(AL[(size_t)src_n * 16 + hd]) + ald;
                    e_n = __expf(t > 0.f ? t : NEG_SLOPE * t);
                }

                sW8[wid][lane] = e_c;  // stats layout [e&7]*8+hd, same-wave consume
                s_run += e_c;
#pragma unroll
                for (int j = 0; j < 4; ++j) {
                    float4 a4 = *(const float4*)&sW8[wid][j * 8 + 4 * eh];
                    float2 alo = make_float2(a4.x, a4.y);
                    float2 ahi = make_float2(a4.z, a4.w);
                    unsigned int u = xv0[j];
                    float2 x2 = make_float2(__uint_as_float(u << 16),
                                            __uint_as_float(u & 0xffff0000u));
                    asm("v_pk_fma_f32 %0, %1, %2, %0 op_sel:[0,0,0] op_sel_hi:[0,1,1]"
                        : "+v"(acc0) : "v"(alo), "v"(x2));
                    asm("v_pk_fma_f32 %0, %1, %2, %0 op_sel:[1,0,0] op_sel_hi:[1,1,1]"
                        : "+v"(acc1) : "v"(alo), "v"(x2));
                    asm("v_pk_fma_f32 %0, %1, %2, %0 op_sel:[0,0,0] op_sel_hi:[0,1,1]"
                        : "+v"(acc2) : "v"(ahi), "v"(x2));
                    asm("v_pk_fma_f32 %0, %1, %2, %0 op_sel:[1,0,0] op_sel_hi:[1,1,1]"
                        : "+v"(acc3) : "v"(ahi), "v"(x2));
                }
#pragma unroll
                for (int j = 0; j < 4; ++j) {
                    int sj = __shfl(src_c, (j + 4) * 8);
                    xv0[j] = *(const unsigned int*)&Xb[(size_t)sj * 64 + 2 * dp];
                }
#pragma unroll
                for (int j = 0; j < 4; ++j) {
                    float4 a4 = *(const float4*)&sW8[wid][(j + 4) * 8 + 4 * eh];
                    float2 alo = make_float2(a4.x, a4.y);
                    float2 ahi = make_float2(a4.z, a4.w);
                    unsigned int u = xv0[j];
                    float2 x2 = make_float2(__uint_as_float(u << 16),
                                            __uint_as_float(u & 0xffff0000u));
                    asm("v_pk_fma_f32 %0, %1, %2, %0 op_sel:[0,0,0] op_sel_hi:[0,1,1]"
                        : "+v"(acc0) : "v"(alo), "v"(x2));
                    asm("v_pk_fma_f32 %0, %1, %2, %0 op_sel:[1,0,0] op_sel_hi:[1,1,1]"
                        : "+v"(acc1) : "v"(alo), "v"(x2));
                    asm("v_pk_fma_f32 %0, %1, %2, %0 op_sel:[0,0,0] op_sel_hi:[0,1,1]"
                        : "+v"(acc2) : "v"(ahi), "v"(x2));
                    asm("v_pk_fma_f32 %0, %1, %2, %0 op_sel:[1,0,0] op_sel_hi:[1,1,1]"
                        : "+v"(acc3) : "v"(ahi), "v"(x2));
                }
                src_c = src_n; e_c = e_n;
            }
#pragma unroll
            for (int d = 8; d <= 32; d <<= 1) s_run += __shfl_xor(s_run, d);
            float sv0 = __shfl(s_run, 4 * eh + 0); float iv0 = 1.0f / (sv0 + 1e-16f);
            float sv1 = __shfl(s_run, 4 * eh + 1); float iv1 = 1.0f / (sv1 + 1e-16f);
            float sv2 = __shfl(s_run, 4 * eh + 2); float iv2 = 1.0f / (sv2 + 1e-16f);
            float sv3 = __shfl(s_run, 4 * eh + 3); float iv3 = 1.0f / (sv3 + 1e-16f);
            acc0.x *= iv0; acc0.y *= iv0;
            acc1.x *= iv1; acc1.y *= iv1;
            acc2.x *= iv2; acc2.y *= iv2;
            acc3.x *= iv3; acc3.y *= iv3;
        }
        // A[mrow][K]: K=(4eh+h2)*64+2dp; chunk=K>>3; rot row (mrow+chunk)&15
        float2 av[4] = {acc0, acc1, acc2, acc3};
#pragma unroll
        for (int h2 = 0; h2 < 4; ++h2) {
            int K0 = (4 * eh + h2) * 64 + 2 * dp;
            int chunk = K0 >> 3, pos = K0 & 7;
            ushort2 w;
            w.x = f2bf(av[h2].x); w.y = f2bf(av[h2].y);
            *(ushort2*)&sA[chunk * 128 + ((mrow + chunk) & 15) * 8 + pos] = w;
        }
    }
    __syncthreads();

    // ---- MFMA projection: waves 0..2 each one 16-col N-tile, K=512
    if (wid < 3) {
        f32x4 cacc = {0.f, 0.f, 0.f, 0.f};
        int grp = lane >> 4;
        int r16 = lane & 15;
#pragma unroll 4
        for (int ks = 0; ks < 16; ++ks) {
            int c = ks * 4 + grp;
            short8v avv = *(const short8v*)&sA[c * 128 + ((r16 + c) & 15) * 8];
            short8v bv = *(const short8v*)&w2sw[(size_t)(c * 48 + wid * 16 + r16) * 8];
            cacc = __builtin_amdgcn_mfma_f32_16x16x32_bf16(avv, bv, cacc, 0, 0, 0);
        }
#pragma unroll
        for (int jj = 0; jj < 4; ++jj)
            sC[grp * 4 + jj][wid * 16 + r16] = cacc[jj];
    }
    __syncthreads();

    // ---- epilogue: + skip, log_softmax over 40 outputs
    for (int p = 0; p < 4; ++p) {
        int mrow = wid * 4 + p;
        int n = blockIdx.x * 16 + mrow;
        if (n >= N) continue;
        float val = (lane < 40) ? SK[(size_t)n * 40 + lane] + sC[mrow][lane] * 0.125f : -INFINITY;
        float mx = val;
#pragma unroll
        for (int d = 32; d; d >>= 1) mx = fmaxf(mx, __shfl_xor(mx, d));
        float ex = (lane < 40) ? __expf(val - mx) : 0.f;
        float sm = ex;
#pragma unroll
        for (int d = 32; d; d >>= 1) sm += __shfl_xor(sm, d);
        if (lane < 40) out[(size_t)n * 40 + lane] = val - mx - logf(sm);
    }
}

// ---------------------------------------------------------------- launch
extern "C" void kernel_launch(void* const* d_in, const int* in_sizes, int n_in,
                              void* d_out, int out_size, void* d_ws, size_t ws_size,
                              hipStream_t stream) {
    const float* x   = (const float*)d_in[0];
    const int*   ei  = (const int*)d_in[1];
    const float* W0  = (const float*)d_in[2];
    const float* as0 = (const float*)d_in[3];
    const float* ad0 = (const float*)d_in[4];
    const float* b0  = (const float*)d_in[5];
    const float* sW0 = (const float*)d_in[6];
    const float* sb0 = (const float*)d_in[7];
    const float* W1  = (const float*)d_in[8];
    const float* as1 = (const float*)d_in[9];
    const float* ad1 = (const float*)d_in[10];
    const float* b1  = (const float*)d_in[11];
    const float* sW1 = (const float*)d_in[12];
    const float* sb1 = (const float*)d_in[13];
    const float* W2  = (const float*)d_in[14];
    const float* as2 = (const float*)d_in[15];
    const float* ad2 = (const float*)d_in[16];
    const float* b2  = (const float*)d_in[17];
    const float* sW2 = (const float*)d_in[18];
    const float* sb2 = (const float*)d_in[19];
    float* out = (float*)d_out;

    int N = in_sizes[0] / 128;
    int E = in_sizes[1] / 2;
    int NBIN = (N + PBIN - 1) >> PBITS;

    char* wsp = (char*)d_ws;
    size_t woff = 0;
    auto A = [&](size_t nbytes) -> void* {
        void* p = wsp + woff;
        woff = (woff + nbytes + 255) & ~(size_t)255;
        return p;
    };
    int* offs   = (int*)A((size_t)(N + 1) * 4);
    int* deg    = (int*)A((size_t)N * 4);
    int* bsum   = (int*)A(4096);
    int* binTot = (int*)A((size_t)(NBIN + 1) * 4);
    int* csr    = (int*)A((size_t)(E + N) * 4);
    int2* rec   = (int2*)A((size_t)NBIN * CAP * 8);
    float* wt   = (float*)A(1024 * 4);
    __hip_bfloat16* w2sw = (__hip_bfloat16*)A(64 * 48 * 8 * 2);
    unsigned short* AL = (unsigned short*)A((size_t)N * 16 * 2);
    float* S    = (float*)A((size_t)N * 64 * 4);
    float* T    = (float*)A((size_t)N * 64 * 4);
    unsigned short* Hb = (unsigned short*)A((size_t)N * 64 * 2);
    unsigned short* Tb = (unsigned short*)A((size_t)N * 64 * 2);
    (void)ws_size; (void)n_in; (void)out_size;

    // ---- CSR build (LDS-staged counting-sort partition)
    hipMemsetAsync(deg, 0, (size_t)N * 4, stream);
    hipMemsetAsync(binTot, 0, (size_t)(NBIN + 1) * 4, stream);
    int gPart = (E + CHUNK - 1) / CHUNK;
    k_part<<<gPart, 256, 0, stream>>>(ei, deg, binTot, rec, E);
    int nb = (N + 1023) / 1024;
    k_scan_block<<<nb, 256, 0, stream>>>(deg, offs, bsum, N);
    k_scan_top<<<1, 256, 0, stream>>>(bsum, nb);
    k_scan_add<<<(N + 255) / 256, 256, 0, stream>>>(offs, bsum, N);
    k_build<<<NBIN, 256, 0, stream>>>(rec, binTot, offs, csr, N);

    // ---- layer-2 constants (independent)
    k_prep2<<<97, 256, 0, stream>>>(W2, as2, ad2, wt, w2sw);

    dim3 bG(16, 16);
    int gG = (N + 63) / 64;
    int gN4 = (N + 3) / 4;

    // ---- layer 0 (input x [N,128]): Hb + S(skip+biases) + AL(bf16) in one GEMM
    k_gemm_dual<8, 64, 64, true, true><<<gG, bG, 0, stream>>>(
        x, W0, sW0, b0, sb0, Hb, S, as0, ad0, AL, N, 128);
    k_fused<<<gN4, 256, 0, stream>>>(Hb, AL, offs, csr, S, nullptr, N);  // S <- x1

    // ---- layer 1 (input S [N,64])
    k_gemm_dual<8, 64, 64, true, true><<<gG, bG, 0, stream>>>(
        S, W1, sW1, b1, sb1, Hb, T, as1, ad1, AL, N, 64);
    k_fused<<<gN4, 256, 0, stream>>>(Hb, AL, offs, csr, T, Tb, N);       // T <- x2 (+bf16 Tb)

    // ---- layer 2 (input T [N,64]): AL(wt part, bf16) + S(skip) in one GEMM
    k_gemm_dual<4, 16, 40, false, true><<<gG, bG, 0, stream>>>(
        T, wt, sW2, b2, sb2, AL, S, nullptr, nullptr, nullptr, N, 64);
    k_l2f<<<(N + 15) / 16, 256, 0, stream>>>(Tb, AL, S, w2sw, offs, csr, out, N);
}

// Round 16
// 477.951 us; speedup vs baseline: 1.4454x; 1.0130x over previous
//
#include <hip/hip_runtime.h>
#include <hip/hip_bf16.h>
#include <math.h>

#define HEADS 8
#define NEG_SLOPE 0.2f
#define PBITS 9
#define PBIN 512              // nodes per coarse bin
#define CHUNK 8192            // edges per k_part block
#define CAP 9216              // record capacity per bin (Poisson(8163)+8 sigma)

typedef __attribute__((ext_vector_type(8))) short short8v;
typedef __attribute__((ext_vector_type(4))) float f32x4;

__device__ __forceinline__ float bf2f(unsigned short u) {
    return __uint_as_float(((unsigned int)u) << 16);
}
__device__ __forceinline__ unsigned short f2bf(float f) {
    __hip_bfloat16 h = __float2bfloat16(f);
    union { __hip_bfloat16 h; unsigned short u; } c; c.h = h; return c.u;
}

// ---------------------------------------------------------------- CSR pass A:
// per-block LDS counting sort by coarse bin; contiguous per-bin runs written
// to globally reserved ranges -> ~1.2x write amplification instead of ~17x.
__global__ __launch_bounds__(256) void k_part(
    const int* __restrict__ ei, int* __restrict__ deg,
    int* __restrict__ binTot, int2* __restrict__ rec, int E) {
    __shared__ int hist[256];
    __shared__ int scanb[256];
    __shared__ int binStart[256];
    __shared__ int cursor[256];
    __shared__ int gbase[256];
    __shared__ int2 stag[CHUNK];   // 64 KB
    int tid = threadIdx.x;
    int base = blockIdx.x * CHUNK;

    hist[tid] = 0;
    __syncthreads();
#pragma unroll 1
    for (int k = 0; k < CHUNK / 256; ++k) {
        int i = base + k * 256 + tid;
        if (i < E) {
            int d = ei[E + i];
            atomicAdd(&hist[d >> PBITS], 1);
            atomicAdd(&deg[d], 1);
        }
    }
    __syncthreads();
    int val = hist[tid];
    scanb[tid] = val;
    __syncthreads();
    for (int off = 1; off < 256; off <<= 1) {
        int x = 0;
        if (tid >= off) x = scanb[tid - off];
        __syncthreads();
        scanb[tid] += x;
        __syncthreads();
    }
    int excl = scanb[tid] - val;
    binStart[tid] = excl;
    cursor[tid] = excl;
    if (val > 0) gbase[tid] = atomicAdd(&binTot[tid], val);
    __syncthreads();
    int total = scanb[255];
#pragma unroll 1
    for (int k = 0; k < CHUNK / 256; ++k) {
        int i = base + k * 256 + tid;
        if (i < E) {
            int s = ei[i], d = ei[E + i];
            int pos = atomicAdd(&cursor[d >> PBITS], 1);
            stag[pos] = make_int2(s, d);
        }
    }
    __syncthreads();
#pragma unroll 1
    for (int idx = tid; idx < total; idx += 256) {
        int2 r = stag[idx];
        int b = r.y >> PBITS;
        int gp = gbase[b] + (idx - binStart[b]);
        if (gp < CAP) rec[(size_t)b * CAP + gp] = r;
    }
}

// deg[] holds edge counts (zeroed by memset); +1 here accounts the self-loop.
__global__ void k_scan_block(const int* __restrict__ deg, int* __restrict__ offs,
                             int* __restrict__ bsum, int N) {
    __shared__ int lds[256];
    int tid = threadIdx.x;
    int base = blockIdx.x * 1024 + tid * 4;
    int v0 = (base + 0 < N) ? deg[base + 0] + 1 : 0;
    int v1 = (base + 1 < N) ? deg[base + 1] + 1 : 0;
    int v2 = (base + 2 < N) ? deg[base + 2] + 1 : 0;
    int v3 = (base + 3 < N) ? deg[base + 3] + 1 : 0;
    int t01 = v0 + v1;
    int tot = t01 + v2 + v3;
    lds[tid] = tot;
    __syncthreads();
    for (int off = 1; off < 256; off <<= 1) {
        int x = 0;
        if (tid >= off) x = lds[tid - off];
        __syncthreads();
        lds[tid] += x;
        __syncthreads();
    }
    int ex = lds[tid] - tot;
    if (tid == 255) bsum[blockIdx.x] = lds[255];
    if (base + 0 < N) offs[base + 0] = ex;
    if (base + 1 < N) offs[base + 1] = ex + v0;
    if (base + 2 < N) offs[base + 2] = ex + t01;
    if (base + 3 < N) offs[base + 3] = ex + t01 + v2;
}

// single 256-thread block scan over nb (<=256) block sums
__global__ void k_scan_top(int* __restrict__ bsum, int nb) {
    __shared__ int lds[256];
    int tid = threadIdx.x;
    int v = (tid < nb) ? bsum[tid] : 0;
    lds[tid] = v;
    __syncthreads();
    for (int off = 1; off < 256; off <<= 1) {
        int x = 0;
        if (tid >= off) x = lds[tid - off];
        __syncthreads();
        lds[tid] += x;
        __syncthreads();
    }
    if (tid < nb) bsum[tid] = lds[tid] - v;  // exclusive
    if (tid == 0) bsum[nb] = lds[255];       // total
}

__global__ void k_scan_add(int* __restrict__ offs, const int* __restrict__ bsum, int N) {
    int i = blockIdx.x * 256 + threadIdx.x;
    if (i < N) offs[i] += bsum[i >> 10];
    if (i == 0) offs[N] = bsum[(N + 1023) >> 10];
}

// ---------------------------------------------------------------- CSR pass B
__global__ __launch_bounds__(256) void k_build(
    const int2* __restrict__ rec, const int* __restrict__ binTot,
    const int* __restrict__ offs, int* __restrict__ csr, int N) {
    __shared__ int loff[PBIN];
    __shared__ int lcnt[PBIN];
    int b = blockIdx.x;
    int tid = threadIdx.x;
    int n0 = b << PBITS;
    for (int q = tid; q < PBIN; q += 256) {
        lcnt[q] = 0;
        int n = n0 + q;
        if (n < N) {
            int o = offs[n];
            loff[q] = o;
            csr[o] = n;          // self-loop first
        }
    }
    __syncthreads();
    int cnt = min(binTot[b], CAP);
    const int2* basep = rec + (size_t)b * CAP;
#pragma unroll 1
    for (int i = tid; i < cnt; i += 256) {
        int2 r = basep[i];
        int l = r.y & (PBIN - 1);
        int rank = atomicAdd(&lcnt[l], 1);
        csr[loff[l] + 1 + rank] = r.x;
    }
}

// ---------------------------------------------------------------- dual GEMM (+ optional AL fold, AL in bf16)
template <int CPT, int M1, int M2, bool AL_FOLD, bool A_BF16>
__global__ __launch_bounds__(256) void k_gemm_dual(
    const float* __restrict__ X, const float* __restrict__ Wa, const float* __restrict__ Wb,
    const float* __restrict__ bias1, const float* __restrict__ bias2,
    void* __restrict__ outa_, float* __restrict__ outb,
    const float* __restrict__ as_w, const float* __restrict__ ad_w,
    unsigned short* __restrict__ AL, int N, int K) {
    constexpr int M = M1 + M2;
    static_assert(CPT * 16 >= M, "CPT too small");
    __shared__ float sW[CPT * 16][68];
    __shared__ float sX[64][68];
    int tx = threadIdx.x, ty = threadIdx.y;
    int tid = ty * 16 + tx;
    int r0 = blockIdx.x * 64;

    float acc[4][CPT];
#pragma unroll
    for (int jc = 0; jc < CPT; ++jc) {
        int col = tx + 16 * jc;
        float b = 0.f;
        if (col >= M1 && col < M) b = bias1[col - M1] + bias2[col - M1];
#pragma unroll
        for (int jr = 0; jr < 4; ++jr) acc[jr][jc] = b;
    }

    for (int k0 = 0; k0 < K; k0 += 64) {
        __syncthreads();
        for (int idx = tid; idx < CPT * 16 * 16; idx += 256) {
            int c = idx >> 4, kq = (idx & 15) * 4;
            float4 v = make_float4(0.f, 0.f, 0.f, 0.f);
            if (c < M1) v = *(const float4*)&Wa[(size_t)c * K + k0 + kq];
            else if (c < M) v = *(const float4*)&Wb[(size_t)(c - M1) * K + k0 + kq];
            *(float4*)&sW[c][kq] = v;
        }
        for (int idx = tid; idx < 64 * 16; idx += 256) {
            int r = idx >> 4, kq = (idx & 15) * 4;
            int gr = r0 + r;
            float4 v = make_float4(0.f, 0.f, 0.f, 0.f);
            if (gr < N) v = *(const float4*)&X[(size_t)gr * K + k0 + kq];
            *(float4*)&sX[r][kq] = v;
        }
        __syncthreads();

        for (int k = 0; k < 64; k += 4) {
            float4 xr[4];
#pragma unroll
            for (int jr = 0; jr < 4; ++jr) xr[jr] = *(const float4*)&sX[ty * 4 + jr][k];
#pragma unroll
            for (int jc = 0; jc < CPT; ++jc) {
                float4 wc = *(const float4*)&sW[tx + 16 * jc][k];
#pragma unroll
                for (int jr = 0; jr < 4; ++jr)
                    acc[jr][jc] += wc.x * xr[jr].x + wc.y * xr[jr].y +
                                   wc.z * xr[jr].z + wc.w * xr[jr].w;
            }
        }
    }

#pragma unroll
    for (int jr = 0; jr < 4; ++jr) {
        int gr = r0 + ty * 4 + jr;
        if (gr >= N) continue;
#pragma unroll
        for (int jc = 0; jc < CPT; ++jc) {
            int col = tx + 16 * jc;
            if (col < M1) {
                if (A_BF16) ((unsigned short*)outa_)[(size_t)gr * M1 + col] = f2bf(acc[jr][jc]);
                else        ((float*)outa_)[(size_t)gr * M1 + col] = acc[jr][jc];
            } else if (col < M) {
                outb[(size_t)gr * M2 + (col - M1)] = acc[jr][jc];
            }
        }
    }

    if constexpr (AL_FOLD) {
        __syncthreads();
        float* sH = &sW[0][0];  // reuse as sH[64][68]
#pragma unroll
        for (int jr = 0; jr < 4; ++jr)
#pragma unroll
            for (int jc = 0; jc < 4; ++jc)
                sH[(ty * 4 + jr) * 68 + (tx + 16 * jc)] = acc[jr][jc];
        __syncthreads();
        int j = tid & 15, hd = j & 7;
        const float* a = (j < 8 ? as_w : ad_w) + hd * 8;
        float av[8];
#pragma unroll
        for (int c = 0; c < 8; ++c) av[c] = a[c];
#pragma unroll
        for (int q = 0; q < 4; ++q) {
            int row = (tid >> 4) + 16 * q;
            int gr = r0 + row;
            if (gr < N) {
                float sum = 0.f;
#pragma unroll
                for (int c = 0; c < 8; ++c) sum += av[c] * sH[row * 68 + hd * 8 + c];
                AL[(size_t)gr * 16 + j] = f2bf(sum);
            }
        }
    }
}

// ---------------------------------------------------------------- layer-2 constant prep
__global__ void k_prep2(const float* __restrict__ W2, const float* __restrict__ as2,
                        const float* __restrict__ ad2, float* __restrict__ wt,
                        __hip_bfloat16* __restrict__ w2sw) {
    if (blockIdx.x < 96) {
        int t = blockIdx.x * 256 + threadIdx.x;
        int j = t & 7;
        int rc = t >> 3;
        int col = rc % 48, c = rc / 48;
        int k = c * 8 + j;
        int hd = k >> 6, kk = k & 63;
        float v = (col < 40) ? W2[(size_t)(hd * 40 + col) * 64 + kk] : 0.f;
        w2sw[t] = __float2bfloat16(v);
    } else {
        for (int t = threadIdx.x; t < 1024; t += 256) {
            int j = t >> 6, k = t & 63;
            int hd = j & 7;
            const float* a = (j < 8 ? as2 : ad2) + hd * 40;
            float sum = 0.f;
            for (int c = 0; c < 40; ++c) sum += a[c] * W2[(size_t)(hd * 40 + c) * 64 + k];
            wt[j * 64 + k] = sum;
        }
    }
}

// ---------------------------------------------------------------- layers 0/1: no-max softmax-aggregate, bf16 rows + bf16 AL
__global__ __launch_bounds__(256, 8) void k_fused(
    const unsigned short* __restrict__ Hb, const unsigned short* __restrict__ AL,
    const int* __restrict__ offs, const int* __restrict__ csr,
    float* __restrict__ S, unsigned short* __restrict__ Sb, int N) {
    int wid = threadIdx.x >> 6, lane = threadIdx.x & 63;
    int n = blockIdx.x * 4 + wid;
    if (n >= N) return;
    int off = offs[n], deg = offs[n + 1] - off;
    int el = lane >> 3, hd = lane & 7;
    int dp = lane & 31, es = lane >> 5;
    int hp = dp >> 2;  // head of dims (2dp,2dp+1)
    float ald = bf2f(AL[(size_t)n * 16 + 8 + hd]);

    int src_c = 0; float e_c = 0.f;
    if (el < deg) {
        src_c = csr[off + el];
        float t = bf2f(AL[(size_t)src_c * 16 + hd]) + ald;
        e_c = __expf(t > 0.f ? t : NEG_SLOPE * t);
    }

    float s_run = 0.f, ax = 0.f, ay = 0.f;
    for (int b0 = 0; b0 < deg; b0 += 8) {
        unsigned int hv[4];
#pragma unroll
        for (int j = 0; j < 4; ++j) {
            int sj = __shfl(src_c, (2 * j + es) * 8);
            hv[j] = *(const unsigned int*)&Hb[(size_t)sj * 64 + 2 * dp];
        }
        // prefetch next block's (src, e)
        int en = b0 + 8 + el;
        int src_n = 0; float e_n = 0.f;
        if (en < deg) {
            src_n = csr[off + en];
            float t = bf2f(AL[(size_t)src_n * 16 + hd]) + ald;
            e_n = __expf(t > 0.f ? t : NEG_SLOPE * t);
        }

        s_run += e_c;  // lane-local; reduced after the loop
#pragma unroll
        for (int j = 0; j < 4; ++j) {
            float a = __shfl(e_c, (2 * j + es) * 8 + hp);
            unsigned int u = hv[j];
            ax += a * bf2f((unsigned short)(u & 0xffff));
            ay += a * bf2f((unsigned short)(u >> 16));
        }
        src_c = src_n; e_c = e_n;
    }
#pragma unroll
    for (int d = 8; d <= 32; d <<= 1) s_run += __shfl_xor(s_run, d);
    float sf = __shfl(s_run, hp);
    float inv = 1.0f / (sf + 1e-16f);
    ax *= inv; ay *= inv;
    ax += __shfl_xor(ax, 32);
    ay += __shfl_xor(ay, 32);
    if (es == 0) {
        float2 sk = *(const float2*)&S[(size_t)n * 64 + 2 * dp];
        float vx = sk.x + ax, vy = sk.y + ay;
        vx = vx > 0.f ? vx : expm1f(vx);
        vy = vy > 0.f ? vy : expm1f(vy);
        *(float2*)&S[(size_t)n * 64 + 2 * dp] = make_float2(vx, vy);
        if (Sb) {
            ushort2 w;
            w.x = f2bf(vx); w.y = f2bf(vy);
            *(ushort2*)&Sb[(size_t)n * 64 + 2 * dp] = w;
        }
    }
}

// ---------------------------------------------------------------- layer 2: no-max aggregate, bf16 rows + bf16 AL, compiler-scheduled FMAs
__global__ __launch_bounds__(256, 8) void k_l2f(
    const unsigned short* __restrict__ Xb, const unsigned short* __restrict__ AL,
    const float* __restrict__ SK, const __hip_bfloat16* __restrict__ w2sw,
    const int* __restrict__ offs, const int* __restrict__ csr,
    float* __restrict__ out, int N) {
    __shared__ __hip_bfloat16 sA[64 * 16 * 8];  // [chunk][rot-row][8], 16 KB
    __shared__ float sC[16][48];                // 3 KB
    __shared__ float sW8[4][64];                // per-wave alpha row, 1 KB
    int wid = threadIdx.x >> 6, lane = threadIdx.x & 63;
    int el = lane >> 3, hd = lane & 7;
    int dp = lane & 31, eh = lane >> 5;

#pragma unroll 1
    for (int p = 0; p < 4; ++p) {
        int mrow = wid * 4 + p;
        int n = blockIdx.x * 16 + mrow;
        float2 acc[4];
#pragma unroll
        for (int h2 = 0; h2 < 4; ++h2) acc[h2] = make_float2(0.f, 0.f);
        if (n < N) {
            int off = offs[n], deg = offs[n + 1] - off;
            float ald = bf2f(AL[(size_t)n * 16 + 8 + hd]);

            int src_c = 0; float e_c = 0.f;
            if (el < deg) {
                src_c = csr[off + el];
                float t = bf2f(AL[(size_t)src_c * 16 + hd]) + ald;
                e_c = __expf(t > 0.f ? t : NEG_SLOPE * t);
            }

            float s_run = 0.f;
#pragma unroll 1
            for (int b0 = 0; b0 < deg; b0 += 8) {
                unsigned int xv0[4];
#pragma unroll
                for (int j = 0; j < 4; ++j) {
                    int sj = __shfl(src_c, j * 8);
                    xv0[j] = *(const unsigned int*)&Xb[(size_t)sj * 64 + 2 * dp];
                }
                // prefetch next block's (src, e)
                int en = b0 + 8 + el;
                int src_n = 0; float e_n = 0.f;
                if (en < deg) {
                    src_n = csr[off + en];
                    float t = bf2f(AL[(size_t)src_n * 16 + hd]) + ald;
                    e_n = __expf(t > 0.f ? t : NEG_SLOPE * t);
                }

                sW8[wid][lane] = e_c;  // stats layout [e&7]*8+hd, same-wave consume
                s_run += e_c;
#pragma unroll
                for (int j = 0; j < 4; ++j) {
                    float4 a4 = *(const float4*)&sW8[wid][j * 8 + 4 * eh];
                    float hx = bf2f((unsigned short)(xv0[j] & 0xffff));
                    float hy = bf2f((unsigned short)(xv0[j] >> 16));
                    acc[0].x += a4.x * hx; acc[0].y += a4.x * hy;
                    acc[1].x += a4.y * hx; acc[1].y += a4.y * hy;
                    acc[2].x += a4.z * hx; acc[2].y += a4.z * hy;
                    acc[3].x += a4.w * hx; acc[3].y += a4.w * hy;
                }
#pragma unroll
                for (int j = 0; j < 4; ++j) {
                    int sj = __shfl(src_c, (j + 4) * 8);
                    xv0[j] = *(const unsigned int*)&Xb[(size_t)sj * 64 + 2 * dp];
                }
#pragma unroll
                for (int j = 0; j < 4; ++j) {
                    float4 a4 = *(const float4*)&sW8[wid][(j + 4) * 8 + 4 * eh];
                    float hx = bf2f((unsigned short)(xv0[j] & 0xffff));
                    float hy = bf2f((unsigned short)(xv0[j] >> 16));
                    acc[0].x += a4.x * hx; acc[0].y += a4.x * hy;
                    acc[1].x += a4.y * hx; acc[1].y += a4.y * hy;
                    acc[2].x += a4.z * hx; acc[2].y += a4.z * hy;
                    acc[3].x += a4.w * hx; acc[3].y += a4.w * hy;
                }
                src_c = src_n; e_c = e_n;
            }
#pragma unroll
            for (int d = 8; d <= 32; d <<= 1) s_run += __shfl_xor(s_run, d);
#pragma unroll
            for (int h2 = 0; h2 < 4; ++h2) {
                float sv = __shfl(s_run, 4 * eh + h2);
                float iv = 1.0f / (sv + 1e-16f);
                acc[h2].x *= iv; acc[h2].y *= iv;
            }
        }
#pragma unroll
        for (int h2 = 0; h2 < 4; ++h2) {
            int K0 = (4 * eh + h2) * 64 + 2 * dp;
            int chunk = K0 >> 3, pos = K0 & 7;
            ushort2 w;
            w.x = f2bf(acc[h2].x); w.y = f2bf(acc[h2].y);
            *(ushort2*)&sA[chunk * 128 + ((mrow + chunk) & 15) * 8 + pos] = w;
        }
    }
    __syncthreads();

    // ---- MFMA projection: waves 0..2 each one 16-col N-tile, K=512
    if (wid < 3) {
        f32x4 cacc = {0.f, 0.f, 0.f, 0.f};
        int grp = lane >> 4;
        int r16 = lane & 15;
#pragma unroll 4
        for (int ks = 0; ks < 16; ++ks) {
            int c = ks * 4 + grp;
            short8v avv = *(const short8v*)&sA[c * 128 + ((r16 + c) & 15) * 8];
            short8v bv = *(const short8v*)&w2sw[(size_t)(c * 48 + wid * 16 + r16) * 8];
            cacc = __builtin_amdgcn_mfma_f32_16x16x32_bf16(avv, bv, cacc, 0, 0, 0);
        }
#pragma unroll
        for (int jj = 0; jj < 4; ++jj)
            sC[grp * 4 + jj][wid * 16 + r16] = cacc[jj];
    }
    __syncthreads();

    // ---- epilogue: + skip, log_softmax over 40 outputs
    for (int p = 0; p < 4; ++p) {
        int mrow = wid * 4 + p;
        int n = blockIdx.x * 16 + mrow;
        if (n >= N) continue;
        float val = (lane < 40) ? SK[(size_t)n * 40 + lane] + sC[mrow][lane] * 0.125f : -INFINITY;
        float mx = val;
#pragma unroll
        for (int d = 32; d; d >>= 1) mx = fmaxf(mx, __shfl_xor(mx, d));
        float ex = (lane < 40) ? __expf(val - mx) : 0.f;
        float sm = ex;
#pragma unroll
        for (int d = 32; d; d >>= 1) sm += __shfl_xor(sm, d);
        if (lane < 40) out[(size_t)n * 40 + lane] = val - mx - logf(sm);
    }
}

// ---------------------------------------------------------------- launch
extern "C" void kernel_launch(void* const* d_in, const int* in_sizes, int n_in,
                              void* d_out, int out_size, void* d_ws, size_t ws_size,
                              hipStream_t stream) {
    const float* x   = (const float*)d_in[0];
    const int*   ei  = (const int*)d_in[1];
    const float* W0  = (const float*)d_in[2];
    const float* as0 = (const float*)d_in[3];
    const float* ad0 = (const float*)d_in[4];
    const float* b0  = (const float*)d_in[5];
    const float* sW0 = (const float*)d_in[6];
    const float* sb0 = (const float*)d_in[7];
    const float* W1  = (const float*)d_in[8];
    const float* as1 = (const float*)d_in[9];
    const float* ad1 = (const float*)d_in[10];
    const float* b1  = (const float*)d_in[11];
    const float* sW1 = (const float*)d_in[12];
    const float* sb1 = (const float*)d_in[13];
    const float* W2  = (const float*)d_in[14];
    const float* as2 = (const float*)d_in[15];
    const float* ad2 = (const float*)d_in[16];
    const float* b2  = (const float*)d_in[17];
    const float* sW2 = (const float*)d_in[18];
    const float* sb2 = (const float*)d_in[19];
    float* out = (float*)d_out;

    int N = in_sizes[0] / 128;
    int E = in_sizes[1] / 2;
    int NBIN = (N + PBIN - 1) >> PBITS;

    char* wsp = (char*)d_ws;
    size_t woff = 0;
    auto A = [&](size_t nbytes) -> void* {
        void* p = wsp + woff;
        woff = (woff + nbytes + 255) & ~(size_t)255;
        return p;
    };
    int* offs   = (int*)A((size_t)(N + 1) * 4);
    int* deg    = (int*)A((size_t)N * 4);
    int* bsum   = (int*)A(4096);
    int* binTot = (int*)A((size_t)(NBIN + 1) * 4);
    int* csr    = (int*)A((size_t)(E + N) * 4);
    int2* rec   = (int2*)A((size_t)NBIN * CAP * 8);
    float* wt   = (float*)A(1024 * 4);
    __hip_bfloat16* w2sw = (__hip_bfloat16*)A(64 * 48 * 8 * 2);
    unsigned short* AL = (unsigned short*)A((size_t)N * 16 * 2);
    float* S    = (float*)A((size_t)N * 64 * 4);
    float* T    = (float*)A((size_t)N * 64 * 4);
    unsigned short* Hb = (unsigned short*)A((size_t)N * 64 * 2);
    unsigned short* Tb = (unsigned short*)A((size_t)N * 64 * 2);
    (void)ws_size; (void)n_in; (void)out_size;

    // ---- CSR build (LDS-staged counting-sort partition)
    hipMemsetAsync(deg, 0, (size_t)N * 4, stream);
    hipMemsetAsync(binTot, 0, (size_t)(NBIN + 1) * 4, stream);
    int gPart = (E + CHUNK - 1) / CHUNK;
    k_part<<<gPart, 256, 0, stream>>>(ei, deg, binTot, rec, E);
    int nb = (N + 1023) / 1024;
    k_scan_block<<<nb, 256, 0, stream>>>(deg, offs, bsum, N);
    k_scan_top<<<1, 256, 0, stream>>>(bsum, nb);
    k_scan_add<<<(N + 255) / 256, 256, 0, stream>>>(offs, bsum, N);
    k_build<<<NBIN, 256, 0, stream>>>(rec, binTot, offs, csr, N);

    // ---- layer-2 constants (independent)
    k_prep2<<<97, 256, 0, stream>>>(W2, as2, ad2, wt, w2sw);

    dim3 bG(16, 16);
    int gG = (N + 63) / 64;
    int gN4 = (N + 3) / 4;

    // ---- layer 0 (input x [N,128]): Hb + S(skip+biases) + AL(bf16) in one GEMM
    k_gemm_dual<8, 64, 64, true, true><<<gG, bG, 0, stream>>>(
        x, W0, sW0, b0, sb0, Hb, S, as0, ad0, AL, N, 128);
    k_fused<<<gN4, 256, 0, stream>>>(Hb, AL, offs, csr, S, nullptr, N);  // S <- x1

    // ---- layer 1 (input S [N,64])
    k_gemm_dual<8, 64, 64, true, true><<<gG, bG, 0, stream>>>(
        S, W1, sW1, b1, sb1, Hb, T, as1, ad1, AL, N, 64);
    k_fused<<<gN4, 256, 0, stream>>>(Hb, AL, offs, csr, T, Tb, N);       // T <- x2 (+bf16 Tb)

    // ---- layer 2 (input T [N,64]): AL(wt part, bf16) + S(skip) in one GEMM
    k_gemm_dual<4, 16, 40, false, true><<<gG, bG, 0, stream>>>(
        T, wt, sW2, b2, sb2, AL, S, nullptr, nullptr, nullptr, N, 64);
    k_l2f<<<(N + 15) / 16, 256, 0, stream>>>(Tb, AL, S, w2sw, offs, csr, out, N);
}